// Round 4
// baseline (386.962 us; speedup 1.0000x reference)
//
#include <hip/hip_runtime.h>

// GraphSAGE 2-layer, mean aggregation, fp32.
// R3 evidence: fill_kernel 130 µs, WRITE_SIZE 96 MB for 6.4 MB payload —
// random 4B plain stores dirty whole 64B lines (15x write amplification,
// random-writeback bound). Fix: atomicExch slot writes (memory-side,
// payload-only commit — R1 measured atomics at payload-sized WRITE).
// Also: layer 2 transform-first (mean is linear): y2=h@W2l^T, z=h@W2r^T+b2,
// then gather-mean 32-wide rows directly into out (halves gather traffic).

constexpr int N_NODES = 100000;
constexpr int E_HALF  = 800000;
constexpr int CAP     = 64;
constexpr int OVF_CAP = 4096;

typedef short  s16x8 __attribute__((ext_vector_type(8)));
typedef float  f32x4 __attribute__((ext_vector_type(4)));

// ------------- bucket fill: one thread per edge ---------------------------
__global__ __launch_bounds__(256) void fill_kernel(
    const int* __restrict__ ei1, const int* __restrict__ ei2,
    int* __restrict__ cnt, int* __restrict__ slots,
    int* __restrict__ ovf_cnt, int* __restrict__ ovf)
{
    int e = blockIdx.x * 256 + threadIdx.x;
    if (e >= 2 * E_HALF) return;
    int src, dst;
    if (e < E_HALF) { src = ei1[e];  dst = ei1[E_HALF + e]; }
    else { int ee = e - E_HALF; src = ei2[ee]; dst = ei2[E_HALF + ee]; }
    int pos = atomicAdd(&cnt[dst], 1);
    if (pos < CAP) {
        atomicExch(&slots[dst * CAP + pos], src);   // memory-side, no line fill
    } else {
        int o = atomicAdd(ovf_cnt, 1);
        if (o < OVF_CAP) { atomicExch(&ovf[2 * o], src); atomicExch(&ovf[2 * o + 1], dst); }
    }
}

// ------------- gather-mean (64-wide rows): one wave per node --------------
__global__ __launch_bounds__(256) void gather_mean_kernel(
    const float* __restrict__ feat,   // [N,64]
    const int*   __restrict__ cnt,    // [N]
    const int*   __restrict__ slots,  // [N,CAP]
    float*       __restrict__ m)      // [N,64] mean output
{
    int node = blockIdx.x * 4 + (threadIdx.x >> 6);
    int f    = threadIdx.x & 63;
    if (node >= N_NODES) return;
    int c  = cnt[node];
    int cc = c < CAP ? c : CAP;
    int slotv = slots[node * CAP + f];
    float a0 = 0.f, a1 = 0.f, a2 = 0.f, a3 = 0.f;
    int i = 0;
    for (; i + 4 <= cc; i += 4) {
        int s0 = __shfl(slotv, i),     s1 = __shfl(slotv, i + 1);
        int s2 = __shfl(slotv, i + 2), s3 = __shfl(slotv, i + 3);
        a0 += feat[s0 * 64 + f];
        a1 += feat[s1 * 64 + f];
        a2 += feat[s2 * 64 + f];
        a3 += feat[s3 * 64 + f];
    }
    for (; i < cc; i++) a0 += feat[__shfl(slotv, i) * 64 + f];
    float rd = 1.0f / fmaxf((float)c, 1.0f);
    m[node * 64 + f] = (a0 + a1 + a2 + a3) * rd;
}

// ------------- gather-mean (32-wide rows) + add z -> out ------------------
// Wave handles 2 neighbors per load: lanes 0-31 neighbor i, 32-63 neighbor i+1.
__global__ __launch_bounds__(256) void gather_mean32_kernel(
    const float* __restrict__ y2,     // [N,32] transformed features
    const float* __restrict__ z,      // [N,32] self term (bias included)
    const int*   __restrict__ cnt,    // [N]
    const int*   __restrict__ slots,  // [N,CAP]
    float*       __restrict__ out)    // [N,32]
{
    int node = blockIdx.x * 4 + (threadIdx.x >> 6);
    int lane = threadIdx.x & 63;
    int f    = lane & 31;
    int g    = lane >> 5;
    if (node >= N_NODES) return;
    int c  = cnt[node];
    int cc = c < CAP ? c : CAP;
    int slotv = slots[node * CAP + lane];
    float a0 = 0.f, a1 = 0.f;
    int i = 0;
    for (; i + 4 <= cc; i += 4) {    // 2 pairs in flight
        int sA = __shfl(slotv, i + g);
        int sB = __shfl(slotv, i + 2 + g);
        a0 += y2[sA * 32 + f];
        a1 += y2[sB * 32 + f];
    }
    for (; i < cc; i += 2) {
        if (i + g < cc) a0 += y2[__shfl(slotv, i + g) * 32 + f];
    }
    float a = a0 + a1;
    a += __shfl_xor(a, 32);          // combine the two half-wave partials
    if (g == 0) {
        float rd = 1.0f / fmaxf((float)c, 1.0f);
        out[node * 32 + f] = a * rd + z[node * 32 + f];
    }
}

// ------------- overflow fallbacks (expected 0 iterations) -----------------
__global__ __launch_bounds__(256) void ovf_apply_kernel(
    const float* __restrict__ feat, const int* __restrict__ cnt,
    const int* __restrict__ ovf_cnt, const int* __restrict__ ovf,
    float* __restrict__ m)
{
    int n = *ovf_cnt;
    if (n > OVF_CAP) n = OVF_CAP;
    int total = n * 64;
    for (int t = blockIdx.x * 256 + threadIdx.x; t < total; t += gridDim.x * 256) {
        int o = t >> 6, f = t & 63;
        int src = ovf[2 * o], dst = ovf[2 * o + 1];
        float rd = 1.0f / fmaxf((float)cnt[dst], 1.0f);
        atomicAdd(&m[dst * 64 + f], feat[src * 64 + f] * rd);
    }
}

__global__ __launch_bounds__(256) void ovf_apply32_kernel(
    const float* __restrict__ y2, const int* __restrict__ cnt,
    const int* __restrict__ ovf_cnt, const int* __restrict__ ovf,
    float* __restrict__ out)
{
    int n = *ovf_cnt;
    if (n > OVF_CAP) n = OVF_CAP;
    int total = n * 32;
    for (int t = blockIdx.x * 256 + threadIdx.x; t < total; t += gridDim.x * 256) {
        int o = t >> 5, f = t & 31;
        int src = ovf[2 * o], dst = ovf[2 * o + 1];
        float rd = 1.0f / fmaxf((float)cnt[dst], 1.0f);
        atomicAdd(&out[dst * 32 + f], y2[src * 32 + f] * rd);
    }
}

// ------------- hi/lo truncate-split of 8 floats to bf16 frags -------------
__device__ inline void split8(float4 v0, float4 v1, s16x8& hi, s16x8& lo) {
    float vs[8] = {v0.x, v0.y, v0.z, v0.w, v1.x, v1.y, v1.z, v1.w};
    s16x8 h, l;
    #pragma unroll
    for (int j = 0; j < 8; j++) {
        unsigned b  = __float_as_uint(vs[j]);
        float    hf = __uint_as_float(b & 0xFFFF0000u);
        float    r  = vs[j] - hf;            // exact
        h[j] = (short)(b >> 16);
        l[j] = (short)(__float_as_uint(r) >> 16);
    }
    hi = h; lo = l;
}

// ------------- weight prep ------------------------------------------------
// B1: [64,128] = [W1l|W1r] along K.  B2: [64,64] rows 0-31 = W2l, 32-63 = W2r.
__global__ __launch_bounds__(256) void wsplit_kernel(
    const float* __restrict__ W1l, const float* __restrict__ W1r,
    const float* __restrict__ W2l, const float* __restrict__ W2r,
    short* __restrict__ B1hi, short* __restrict__ B1lo,
    short* __restrict__ B2hi, short* __restrict__ B2lo)
{
    int i = blockIdx.x * 256 + threadIdx.x;
    float v; short* ph; short* pl; int idx;
    if (i < 64 * 128) {
        int o = i >> 7, k = i & 127;
        v = (k < 64) ? W1l[o * 64 + k] : W1r[o * 64 + (k - 64)];
        ph = B1hi; pl = B1lo; idx = i;
    } else if (i < 64 * 128 + 64 * 64) {
        int j = i - 64 * 128;
        int o = j >> 6, k = j & 63;
        v = (o < 32) ? W2l[o * 64 + k] : W2r[(o - 32) * 64 + k];
        ph = B2hi; pl = B2lo; idx = j;
    } else return;
    unsigned b  = __float_as_uint(v);
    float    hf = __uint_as_float(b & 0xFFFF0000u);
    float    r  = v - hf;
    ph[idx] = (short)(b >> 16);
    pl[idx] = (short)(__float_as_uint(r) >> 16);
}

// ------------- GEMM layer 1: h = relu([m|x] @ B1^T + b1), K=128 -----------
template <int MT>
__global__ __launch_bounds__(256) void gemm1_kernel(
    const float* __restrict__ Am, const float* __restrict__ Ax,
    const short* __restrict__ Bhi, const short* __restrict__ Blo,
    const float* __restrict__ bias, float* __restrict__ out)
{
    int wave = (blockIdx.x * 256 + threadIdx.x) >> 6;
    int lane = threadIdx.x & 63;
    int m0   = wave * (MT * 16);
    if (m0 >= N_NODES) return;
    int quad = lane >> 4, l16 = lane & 15;

    f32x4 acc[MT][4];
    #pragma unroll
    for (int mt = 0; mt < MT; mt++)
        #pragma unroll
        for (int nt = 0; nt < 4; nt++) acc[mt][nt] = (f32x4)0.0f;

    #pragma unroll
    for (int half = 0; half < 2; half++) {
        const float* src = half ? Ax : Am;
        #pragma unroll
        for (int sub = 0; sub < 2; sub++) {
            int kf = sub * 32 + quad * 8;
            int kc = half * 64 + sub * 32 + quad * 8;
            s16x8 ahi[MT], alo[MT];
            #pragma unroll
            for (int mt = 0; mt < MT; mt++) {
                int row = m0 + mt * 16 + l16;
                row = row < N_NODES ? row : N_NODES - 1;
                const float4* p = (const float4*)&src[row * 64 + kf];
                split8(p[0], p[1], ahi[mt], alo[mt]);
            }
            #pragma unroll
            for (int nt = 0; nt < 4; nt++) {
                int n = nt * 16 + l16;
                s16x8 bh = *(const s16x8*)&Bhi[n * 128 + kc];
                s16x8 bl = *(const s16x8*)&Blo[n * 128 + kc];
                #pragma unroll
                for (int mt = 0; mt < MT; mt++) {
                    acc[mt][nt] = __builtin_amdgcn_mfma_f32_16x16x32_bf16(ahi[mt], bh, acc[mt][nt], 0, 0, 0);
                    acc[mt][nt] = __builtin_amdgcn_mfma_f32_16x16x32_bf16(alo[mt], bh, acc[mt][nt], 0, 0, 0);
                    acc[mt][nt] = __builtin_amdgcn_mfma_f32_16x16x32_bf16(ahi[mt], bl, acc[mt][nt], 0, 0, 0);
                }
            }
        }
    }
    #pragma unroll
    for (int nt = 0; nt < 4; nt++) {
        float bv = bias[nt * 16 + l16];
        #pragma unroll
        for (int mt = 0; mt < MT; mt++)
            #pragma unroll
            for (int r = 0; r < 4; r++) {
                int row = m0 + mt * 16 + quad * 4 + r;
                if (row < N_NODES)
                    out[row * 64 + nt * 16 + l16] = fmaxf(acc[mt][nt][r] + bv, 0.0f);
            }
    }
}

// ------------- GEMM layer 2: y2 = h@W2l^T ; z = h@W2r^T + b2, K=64 --------
template <int MT>
__global__ __launch_bounds__(256) void gemm2_kernel(
    const float* __restrict__ h,
    const short* __restrict__ Bhi, const short* __restrict__ Blo,  // [64,64]
    const float* __restrict__ b2,
    float* __restrict__ y2, float* __restrict__ z)                 // [N,32] each
{
    int wave = (blockIdx.x * 256 + threadIdx.x) >> 6;
    int lane = threadIdx.x & 63;
    int m0   = wave * (MT * 16);
    if (m0 >= N_NODES) return;
    int quad = lane >> 4, l16 = lane & 15;

    f32x4 acc[MT][4];
    #pragma unroll
    for (int mt = 0; mt < MT; mt++)
        #pragma unroll
        for (int nt = 0; nt < 4; nt++) acc[mt][nt] = (f32x4)0.0f;

    #pragma unroll
    for (int sub = 0; sub < 2; sub++) {
        int kf = sub * 32 + quad * 8;
        s16x8 ahi[MT], alo[MT];
        #pragma unroll
        for (int mt = 0; mt < MT; mt++) {
            int row = m0 + mt * 16 + l16;
            row = row < N_NODES ? row : N_NODES - 1;
            const float4* p = (const float4*)&h[row * 64 + kf];
            split8(p[0], p[1], ahi[mt], alo[mt]);
        }
        #pragma unroll
        for (int nt = 0; nt < 4; nt++) {
            int n = nt * 16 + l16;
            s16x8 bh = *(const s16x8*)&Bhi[n * 64 + kf];
            s16x8 bl = *(const s16x8*)&Blo[n * 64 + kf];
            #pragma unroll
            for (int mt = 0; mt < MT; mt++) {
                acc[mt][nt] = __builtin_amdgcn_mfma_f32_16x16x32_bf16(ahi[mt], bh, acc[mt][nt], 0, 0, 0);
                acc[mt][nt] = __builtin_amdgcn_mfma_f32_16x16x32_bf16(alo[mt], bh, acc[mt][nt], 0, 0, 0);
                acc[mt][nt] = __builtin_amdgcn_mfma_f32_16x16x32_bf16(ahi[mt], bl, acc[mt][nt], 0, 0, 0);
            }
        }
    }
    #pragma unroll
    for (int nt = 0; nt < 4; nt++) {
        bool  isz = nt >= 2;
        int   col = (isz ? nt - 2 : nt) * 16 + l16;
        float bv  = isz ? b2[col] : 0.0f;
        float* dst = isz ? z : y2;
        #pragma unroll
        for (int mt = 0; mt < MT; mt++)
            #pragma unroll
            for (int r = 0; r < 4; r++) {
                int row = m0 + mt * 16 + quad * 4 + r;
                if (row < N_NODES) dst[row * 32 + col] = acc[mt][nt][r] + bv;
            }
    }
}

extern "C" void kernel_launch(void* const* d_in, const int* in_sizes, int n_in,
                              void* d_out, int out_size, void* d_ws, size_t ws_size,
                              hipStream_t stream) {
    const float* x   = (const float*)d_in[0];
    const int*   ei1 = (const int*)d_in[1];
    const int*   ei2 = (const int*)d_in[3];
    const float* W1l = (const float*)d_in[5];
    const float* b1  = (const float*)d_in[6];
    const float* W1r = (const float*)d_in[7];
    const float* W2l = (const float*)d_in[8];
    const float* b2  = (const float*)d_in[9];
    const float* W2r = (const float*)d_in[10];
    float* out = (float*)d_out;

    // workspace layout (256B-aligned)
    const size_t off_cnt    = 0;                                   // int[N]
    const size_t off_ovfcnt = 400128;
    const size_t off_ovf    = 400384;                              // int[2*OVF]
    const size_t off_slots  = 433152;                              // int[N*CAP]
    const size_t off_m      = off_slots + (size_t)N_NODES * CAP * 4;
    const size_t off_h      = off_m + (size_t)N_NODES * 64 * 4;
    const size_t off_B1hi   = off_h + (size_t)N_NODES * 64 * 4;
    const size_t off_B1lo   = off_B1hi + 64 * 128 * 2;
    const size_t off_B2hi   = off_B1lo + 64 * 128 * 2;
    const size_t off_B2lo   = off_B2hi + 64 * 64 * 2;

    char* ws = (char*)d_ws;
    int*   cnt     = (int*)(ws + off_cnt);
    int*   ovf_cnt = (int*)(ws + off_ovfcnt);
    int*   ovf     = (int*)(ws + off_ovf);
    int*   slots   = (int*)(ws + off_slots);
    float* m       = (float*)(ws + off_m);
    float* h       = (float*)(ws + off_h);
    // y2/z alias m (gemm1 has consumed m before gemm2 writes them)
    float* y2      = m;
    float* z       = m + (size_t)N_NODES * 32;
    short* B1hi    = (short*)(ws + off_B1hi);
    short* B1lo    = (short*)(ws + off_B1lo);
    short* B2hi    = (short*)(ws + off_B2hi);
    short* B2lo    = (short*)(ws + off_B2lo);

    hipMemsetAsync(ws, 0, off_slots, stream);   // cnt + ovf header only

    fill_kernel<<<(2 * E_HALF + 255) / 256, 256, 0, stream>>>(
        ei1, ei2, cnt, slots, ovf_cnt, ovf);
    wsplit_kernel<<<48, 256, 0, stream>>>(
        W1l, W1r, W2l, W2r, B1hi, B1lo, B2hi, B2lo);

    // layer 1: gather-mean(x) -> m ; h = relu([m|x]@B1^T + b1)
    gather_mean_kernel<<<N_NODES / 4, 256, 0, stream>>>(x, cnt, slots, m);
    ovf_apply_kernel<<<16, 256, 0, stream>>>(x, cnt, ovf_cnt, ovf, m);
    {
        int waves = (N_NODES + 31) / 32;   // MT=2
        gemm1_kernel<2><<<(waves + 3) / 4, 256, 0, stream>>>(
            m, x, B1hi, B1lo, b1, h);
    }

    // layer 2 (transform-first): y2 = h@W2l^T, z = h@W2r^T + b2;
    // out = gather-mean(y2) + z
    {
        int waves = (N_NODES + 63) / 64;   // MT=4
        gemm2_kernel<4><<<(waves + 3) / 4, 256, 0, stream>>>(
            h, B2hi, B2lo, b2, y2, z);
    }
    gather_mean32_kernel<<<N_NODES / 4, 256, 0, stream>>>(y2, z, cnt, slots, out);
    ovf_apply32_kernel<<<16, 256, 0, stream>>>(y2, cnt, ovf_cnt, ovf, out);
}

// Round 5
// 343.964 us; speedup vs baseline: 1.1250x; 1.1250x over previous
//
#include <hip/hip_runtime.h>

// GraphSAGE 2-layer, mean aggregation, fp32.
// R4 evidence: fill is bound by uncoalesced-transaction rate (~21-25 G/s;
// 3.2M random atomics/stores -> ~130-155 us floor), NOT write bytes;
// atomicExch regressed it — reverted to plain stores. Gathers are the #2
// cost (410/205 MB of L3-resident random row reads) -> read features in
// bf16 (half traffic) with ILP-8. 4-term hi/lo MFMA split restores fp32-
// level GEMM accuracy (R4 absmax was 86% of threshold).

constexpr int N_NODES = 100000;
constexpr int E_HALF  = 800000;
constexpr int CAP     = 64;
constexpr int OVF_CAP = 4096;

typedef short  s16x8 __attribute__((ext_vector_type(8)));
typedef float  f32x4 __attribute__((ext_vector_type(4)));
typedef unsigned short u16;

__device__ inline float bf(u16 u) { return __uint_as_float(((unsigned)u) << 16); }
__device__ inline u16 f2bf(float v) {          // round-to-nearest-even bf16
    unsigned b = __float_as_uint(v);
    b += 0x7FFFu + ((b >> 16) & 1u);
    return (u16)(b >> 16);
}

// ------------- bucket fill: one thread per edge (plain stores) ------------
__global__ __launch_bounds__(256) void fill_kernel(
    const int* __restrict__ ei1, const int* __restrict__ ei2,
    int* __restrict__ cnt, int* __restrict__ slots,
    int* __restrict__ ovf_cnt, int* __restrict__ ovf)
{
    int e = blockIdx.x * 256 + threadIdx.x;
    if (e >= 2 * E_HALF) return;
    int src, dst;
    if (e < E_HALF) { src = ei1[e];  dst = ei1[E_HALF + e]; }
    else { int ee = e - E_HALF; src = ei2[ee]; dst = ei2[E_HALF + ee]; }
    int pos = atomicAdd(&cnt[dst], 1);
    if (pos < CAP) {
        slots[dst * CAP + pos] = src;
    } else {
        int o = atomicAdd(ovf_cnt, 1);
        if (o < OVF_CAP) { ovf[2 * o] = src; ovf[2 * o + 1] = dst; }
    }
}

// ------------- x -> bf16 (RNE), 4 elems/thread ----------------------------
__global__ __launch_bounds__(256) void tobf16_kernel(
    const float* __restrict__ x, u16* __restrict__ xb)
{
    int i = blockIdx.x * 256 + threadIdx.x;     // N*16 threads
    if (i >= N_NODES * 16) return;
    float4 v = ((const float4*)x)[i];
    ushort4 r;
    r.x = f2bf(v.x); r.y = f2bf(v.y); r.z = f2bf(v.z); r.w = f2bf(v.w);
    ((ushort4*)xb)[i] = r;
}

// ------------- gather-mean (bf16 64-wide rows): one wave per node ---------
__global__ __launch_bounds__(256) void gather_mean_kernel(
    const u16*  __restrict__ xb,      // [N,64] bf16
    const int*  __restrict__ cnt,     // [N]
    const int*  __restrict__ slots,   // [N,CAP]
    float*      __restrict__ m)       // [N,64] mean output (fp32)
{
    int node = blockIdx.x * 4 + (threadIdx.x >> 6);
    int f    = threadIdx.x & 63;
    if (node >= N_NODES) return;
    int c  = cnt[node];
    int cc = c < CAP ? c : CAP;
    int slotv = slots[node * CAP + f];
    float a0 = 0.f, a1 = 0.f, a2 = 0.f, a3 = 0.f;
    int i = 0;
    for (; i + 8 <= cc; i += 8) {               // 8 loads in flight
        int s0 = __shfl(slotv, i),     s1 = __shfl(slotv, i + 1);
        int s2 = __shfl(slotv, i + 2), s3 = __shfl(slotv, i + 3);
        int s4 = __shfl(slotv, i + 4), s5 = __shfl(slotv, i + 5);
        int s6 = __shfl(slotv, i + 6), s7 = __shfl(slotv, i + 7);
        u16 v0 = xb[s0 * 64 + f], v1 = xb[s1 * 64 + f];
        u16 v2 = xb[s2 * 64 + f], v3 = xb[s3 * 64 + f];
        u16 v4 = xb[s4 * 64 + f], v5 = xb[s5 * 64 + f];
        u16 v6 = xb[s6 * 64 + f], v7 = xb[s7 * 64 + f];
        a0 += bf(v0) + bf(v4); a1 += bf(v1) + bf(v5);
        a2 += bf(v2) + bf(v6); a3 += bf(v3) + bf(v7);
    }
    for (; i < cc; i++) a0 += bf(xb[__shfl(slotv, i) * 64 + f]);
    float rd = 1.0f / fmaxf((float)c, 1.0f);
    m[node * 64 + f] = (a0 + a1 + a2 + a3) * rd;
}

// ------------- gather-mean (bf16 32-wide rows) + add z -> out -------------
__global__ __launch_bounds__(256) void gather_mean32_kernel(
    const u16*  __restrict__ y2b,     // [N,32] bf16 transformed features
    const float* __restrict__ z,      // [N,32] self term (bias included)
    const int*  __restrict__ cnt,
    const int*  __restrict__ slots,
    float*      __restrict__ out)     // [N,32]
{
    int node = blockIdx.x * 4 + (threadIdx.x >> 6);
    int lane = threadIdx.x & 63;
    int f    = lane & 31;
    int g    = lane >> 5;
    if (node >= N_NODES) return;
    int c  = cnt[node];
    int cc = c < CAP ? c : CAP;
    int slotv = slots[node * CAP + lane];
    float a0 = 0.f, a1 = 0.f, a2 = 0.f, a3 = 0.f;
    int i = 0;
    for (; i + 8 <= cc; i += 8) {               // 4 rows per half-wave in flight
        int sA = __shfl(slotv, i + g);
        int sB = __shfl(slotv, i + 2 + g);
        int sC = __shfl(slotv, i + 4 + g);
        int sD = __shfl(slotv, i + 6 + g);
        u16 vA = y2b[sA * 32 + f], vB = y2b[sB * 32 + f];
        u16 vC = y2b[sC * 32 + f], vD = y2b[sD * 32 + f];
        a0 += bf(vA); a1 += bf(vB); a2 += bf(vC); a3 += bf(vD);
    }
    for (; i < cc; i += 2) {
        if (i + g < cc) a0 += bf(y2b[__shfl(slotv, i + g) * 32 + f]);
    }
    float a = a0 + a1 + a2 + a3;
    a += __shfl_xor(a, 32);
    if (g == 0) {
        float rd = 1.0f / fmaxf((float)c, 1.0f);
        out[node * 32 + f] = a * rd + z[node * 32 + f];
    }
}

// ------------- overflow fallbacks (expected 0 iterations) -----------------
__global__ __launch_bounds__(256) void ovf_apply_kernel(
    const float* __restrict__ feat, const int* __restrict__ cnt,
    const int* __restrict__ ovf_cnt, const int* __restrict__ ovf,
    float* __restrict__ m)
{
    int n = *ovf_cnt;
    if (n > OVF_CAP) n = OVF_CAP;
    int total = n * 64;
    for (int t = blockIdx.x * 256 + threadIdx.x; t < total; t += gridDim.x * 256) {
        int o = t >> 6, f = t & 63;
        int src = ovf[2 * o], dst = ovf[2 * o + 1];
        float rd = 1.0f / fmaxf((float)cnt[dst], 1.0f);
        atomicAdd(&m[dst * 64 + f], feat[src * 64 + f] * rd);
    }
}

__global__ __launch_bounds__(256) void ovf_apply32_kernel(
    const u16* __restrict__ y2b, const int* __restrict__ cnt,
    const int* __restrict__ ovf_cnt, const int* __restrict__ ovf,
    float* __restrict__ out)
{
    int n = *ovf_cnt;
    if (n > OVF_CAP) n = OVF_CAP;
    int total = n * 32;
    for (int t = blockIdx.x * 256 + threadIdx.x; t < total; t += gridDim.x * 256) {
        int o = t >> 5, f = t & 31;
        int src = ovf[2 * o], dst = ovf[2 * o + 1];
        float rd = 1.0f / fmaxf((float)cnt[dst], 1.0f);
        atomicAdd(&out[dst * 32 + f], bf(y2b[src * 32 + f]) * rd);
    }
}

// ------------- hi/lo truncate-split of 8 floats to bf16 frags -------------
__device__ inline void split8(float4 v0, float4 v1, s16x8& hi, s16x8& lo) {
    float vs[8] = {v0.x, v0.y, v0.z, v0.w, v1.x, v1.y, v1.z, v1.w};
    s16x8 h, l;
    #pragma unroll
    for (int j = 0; j < 8; j++) {
        unsigned b  = __float_as_uint(vs[j]);
        float    hf = __uint_as_float(b & 0xFFFF0000u);
        float    r  = vs[j] - hf;            // exact
        h[j] = (short)(b >> 16);
        l[j] = (short)(__float_as_uint(r) >> 16);
    }
    hi = h; lo = l;
}

// ------------- weight prep ------------------------------------------------
// B1: [64,128] = [W1l|W1r] along K.  B2: [64,64] rows 0-31 = W2l, 32-63 = W2r.
__global__ __launch_bounds__(256) void wsplit_kernel(
    const float* __restrict__ W1l, const float* __restrict__ W1r,
    const float* __restrict__ W2l, const float* __restrict__ W2r,
    short* __restrict__ B1hi, short* __restrict__ B1lo,
    short* __restrict__ B2hi, short* __restrict__ B2lo)
{
    int i = blockIdx.x * 256 + threadIdx.x;
    float v; short* ph; short* pl; int idx;
    if (i < 64 * 128) {
        int o = i >> 7, k = i & 127;
        v = (k < 64) ? W1l[o * 64 + k] : W1r[o * 64 + (k - 64)];
        ph = B1hi; pl = B1lo; idx = i;
    } else if (i < 64 * 128 + 64 * 64) {
        int j = i - 64 * 128;
        int o = j >> 6, k = j & 63;
        v = (o < 32) ? W2l[o * 64 + k] : W2r[(o - 32) * 64 + k];
        ph = B2hi; pl = B2lo; idx = j;
    } else return;
    unsigned b  = __float_as_uint(v);
    float    hf = __uint_as_float(b & 0xFFFF0000u);
    float    r  = v - hf;
    ph[idx] = (short)(b >> 16);
    pl[idx] = (short)(__float_as_uint(r) >> 16);
}

// ------------- GEMM layer 1: h = relu([m|x] @ B1^T + b1), K=128 -----------
template <int MT>
__global__ __launch_bounds__(256) void gemm1_kernel(
    const float* __restrict__ Am, const float* __restrict__ Ax,
    const short* __restrict__ Bhi, const short* __restrict__ Blo,
    const float* __restrict__ bias, float* __restrict__ out)
{
    int wave = (blockIdx.x * 256 + threadIdx.x) >> 6;
    int lane = threadIdx.x & 63;
    int m0   = wave * (MT * 16);
    if (m0 >= N_NODES) return;
    int quad = lane >> 4, l16 = lane & 15;

    f32x4 acc[MT][4];
    #pragma unroll
    for (int mt = 0; mt < MT; mt++)
        #pragma unroll
        for (int nt = 0; nt < 4; nt++) acc[mt][nt] = (f32x4)0.0f;

    #pragma unroll
    for (int half = 0; half < 2; half++) {
        const float* src = half ? Ax : Am;
        #pragma unroll
        for (int sub = 0; sub < 2; sub++) {
            int kf = sub * 32 + quad * 8;
            int kc = half * 64 + sub * 32 + quad * 8;
            s16x8 ahi[MT], alo[MT];
            #pragma unroll
            for (int mt = 0; mt < MT; mt++) {
                int row = m0 + mt * 16 + l16;
                row = row < N_NODES ? row : N_NODES - 1;
                const float4* p = (const float4*)&src[row * 64 + kf];
                split8(p[0], p[1], ahi[mt], alo[mt]);
            }
            #pragma unroll
            for (int nt = 0; nt < 4; nt++) {
                int n = nt * 16 + l16;
                s16x8 bh = *(const s16x8*)&Bhi[n * 128 + kc];
                s16x8 bl = *(const s16x8*)&Blo[n * 128 + kc];
                #pragma unroll
                for (int mt = 0; mt < MT; mt++) {
                    acc[mt][nt] = __builtin_amdgcn_mfma_f32_16x16x32_bf16(ahi[mt], bh, acc[mt][nt], 0, 0, 0);
                    acc[mt][nt] = __builtin_amdgcn_mfma_f32_16x16x32_bf16(alo[mt], bh, acc[mt][nt], 0, 0, 0);
                    acc[mt][nt] = __builtin_amdgcn_mfma_f32_16x16x32_bf16(ahi[mt], bl, acc[mt][nt], 0, 0, 0);
                    acc[mt][nt] = __builtin_amdgcn_mfma_f32_16x16x32_bf16(alo[mt], bl, acc[mt][nt], 0, 0, 0);
                }
            }
        }
    }
    #pragma unroll
    for (int nt = 0; nt < 4; nt++) {
        float bv = bias[nt * 16 + l16];
        #pragma unroll
        for (int mt = 0; mt < MT; mt++)
            #pragma unroll
            for (int r = 0; r < 4; r++) {
                int row = m0 + mt * 16 + quad * 4 + r;
                if (row < N_NODES)
                    out[row * 64 + nt * 16 + l16] = fmaxf(acc[mt][nt][r] + bv, 0.0f);
            }
    }
}

// ------------- GEMM layer 2: y2b = bf16(h@W2l^T) ; z = h@W2r^T + b2 -------
template <int MT>
__global__ __launch_bounds__(256) void gemm2_kernel(
    const float* __restrict__ h,
    const short* __restrict__ Bhi, const short* __restrict__ Blo,  // [64,64]
    const float* __restrict__ b2,
    u16* __restrict__ y2b, float* __restrict__ z)                  // [N,32] each
{
    int wave = (blockIdx.x * 256 + threadIdx.x) >> 6;
    int lane = threadIdx.x & 63;
    int m0   = wave * (MT * 16);
    if (m0 >= N_NODES) return;
    int quad = lane >> 4, l16 = lane & 15;

    f32x4 acc[MT][4];
    #pragma unroll
    for (int mt = 0; mt < MT; mt++)
        #pragma unroll
        for (int nt = 0; nt < 4; nt++) acc[mt][nt] = (f32x4)0.0f;

    #pragma unroll
    for (int sub = 0; sub < 2; sub++) {
        int kf = sub * 32 + quad * 8;
        s16x8 ahi[MT], alo[MT];
        #pragma unroll
        for (int mt = 0; mt < MT; mt++) {
            int row = m0 + mt * 16 + l16;
            row = row < N_NODES ? row : N_NODES - 1;
            const float4* p = (const float4*)&h[row * 64 + kf];
            split8(p[0], p[1], ahi[mt], alo[mt]);
        }
        #pragma unroll
        for (int nt = 0; nt < 4; nt++) {
            int n = nt * 16 + l16;
            s16x8 bh = *(const s16x8*)&Bhi[n * 64 + kf];
            s16x8 bl = *(const s16x8*)&Blo[n * 64 + kf];
            #pragma unroll
            for (int mt = 0; mt < MT; mt++) {
                acc[mt][nt] = __builtin_amdgcn_mfma_f32_16x16x32_bf16(ahi[mt], bh, acc[mt][nt], 0, 0, 0);
                acc[mt][nt] = __builtin_amdgcn_mfma_f32_16x16x32_bf16(alo[mt], bh, acc[mt][nt], 0, 0, 0);
                acc[mt][nt] = __builtin_amdgcn_mfma_f32_16x16x32_bf16(ahi[mt], bl, acc[mt][nt], 0, 0, 0);
                acc[mt][nt] = __builtin_amdgcn_mfma_f32_16x16x32_bf16(alo[mt], bl, acc[mt][nt], 0, 0, 0);
            }
        }
    }
    #pragma unroll
    for (int nt = 0; nt < 4; nt++) {
        bool  isz = nt >= 2;
        int   col = (isz ? nt - 2 : nt) * 16 + l16;
        float bv  = isz ? b2[col] : 0.0f;
        #pragma unroll
        for (int mt = 0; mt < MT; mt++)
            #pragma unroll
            for (int r = 0; r < 4; r++) {
                int row = m0 + mt * 16 + quad * 4 + r;
                if (row < N_NODES) {
                    float v = acc[mt][nt][r] + bv;
                    if (isz) z[row * 32 + col] = v;
                    else     y2b[row * 32 + col] = f2bf(v);
                }
            }
    }
}

extern "C" void kernel_launch(void* const* d_in, const int* in_sizes, int n_in,
                              void* d_out, int out_size, void* d_ws, size_t ws_size,
                              hipStream_t stream) {
    const float* x   = (const float*)d_in[0];
    const int*   ei1 = (const int*)d_in[1];
    const int*   ei2 = (const int*)d_in[3];
    const float* W1l = (const float*)d_in[5];
    const float* b1  = (const float*)d_in[6];
    const float* W1r = (const float*)d_in[7];
    const float* W2l = (const float*)d_in[8];
    const float* b2  = (const float*)d_in[9];
    const float* W2r = (const float*)d_in[10];
    float* out = (float*)d_out;

    // workspace layout (256B-aligned). Aliasing plan:
    //   xb  (bf16 x, used before gemm1)   aliases h region
    //   z   (fp32, written by gemm2)      aliases m[0 : N*32 floats]
    //   y2b (bf16, written by gemm2)      aliases m[N*32 : N*48 floats]
    //   (m is dead after gemm1 reads it; xb dead before gemm1 writes h)
    const size_t off_cnt    = 0;                                   // int[N]
    const size_t off_ovfcnt = 400128;
    const size_t off_ovf    = 400384;                              // int[2*OVF]
    const size_t off_slots  = 433152;                              // int[N*CAP]
    const size_t off_m      = off_slots + (size_t)N_NODES * CAP * 4;
    const size_t off_h      = off_m + (size_t)N_NODES * 64 * 4;
    const size_t off_B1hi   = off_h + (size_t)N_NODES * 64 * 4;
    const size_t off_B1lo   = off_B1hi + 64 * 128 * 2;
    const size_t off_B2hi   = off_B1lo + 64 * 128 * 2;
    const size_t off_B2lo   = off_B2hi + 64 * 64 * 2;

    char* ws = (char*)d_ws;
    int*   cnt     = (int*)(ws + off_cnt);
    int*   ovf_cnt = (int*)(ws + off_ovfcnt);
    int*   ovf     = (int*)(ws + off_ovf);
    int*   slots   = (int*)(ws + off_slots);
    float* m       = (float*)(ws + off_m);
    float* h       = (float*)(ws + off_h);
    u16*   xb      = (u16*)(ws + off_h);                           // alias h
    float* z       = (float*)(ws + off_m);                         // alias m
    u16*   y2b     = (u16*)(ws + off_m + (size_t)N_NODES * 32 * 4);// alias m
    short* B1hi    = (short*)(ws + off_B1hi);
    short* B1lo    = (short*)(ws + off_B1lo);
    short* B2hi    = (short*)(ws + off_B2hi);
    short* B2lo    = (short*)(ws + off_B2lo);

    hipMemsetAsync(ws, 0, off_slots, stream);   // cnt + ovf header only

    fill_kernel<<<(2 * E_HALF + 255) / 256, 256, 0, stream>>>(
        ei1, ei2, cnt, slots, ovf_cnt, ovf);
    tobf16_kernel<<<(N_NODES * 16 + 255) / 256, 256, 0, stream>>>(x, xb);
    wsplit_kernel<<<48, 256, 0, stream>>>(
        W1l, W1r, W2l, W2r, B1hi, B1lo, B2hi, B2lo);

    // layer 1: gather-mean(bf16 x) -> m ; h = relu([m|x]@B1^T + b1)
    gather_mean_kernel<<<N_NODES / 4, 256, 0, stream>>>(xb, cnt, slots, m);
    ovf_apply_kernel<<<16, 256, 0, stream>>>(x, cnt, ovf_cnt, ovf, m);
    {
        int waves = (N_NODES + 31) / 32;   // MT=2
        gemm1_kernel<2><<<(waves + 3) / 4, 256, 0, stream>>>(
            m, x, B1hi, B1lo, b1, h);
    }

    // layer 2 (transform-first): y2b = bf16(h@W2l^T), z = h@W2r^T + b2;
    // out = gather-mean(y2b) + z
    {
        int waves = (N_NODES + 63) / 64;   // MT=4
        gemm2_kernel<4><<<(waves + 3) / 4, 256, 0, stream>>>(
            h, B2hi, B2lo, b2, y2b, z);
    }
    gather_mean32_kernel<<<N_NODES / 4, 256, 0, stream>>>(y2b, z, cnt, slots, out);
    ovf_apply32_kernel<<<16, 256, 0, stream>>>(y2b, cnt, ovf_cnt, ovf, out);
}

// Round 6
// 333.589 us; speedup vs baseline: 1.1600x; 1.0311x over previous
//
#include <hip/hip_runtime.h>

// GraphSAGE 2-layer, mean aggregation, fp32.
// R5 evidence: fill WRITE_SIZE 96 MB vs 6.4 MB ideal dirty footprint —
// every XCD L2 caches the full 6.4 MB slot-line set + edge streams > 4 MiB
// capacity -> write-allocate thrash (one dirty eviction per ~2 stores).
// Fix: dst-partitioned fill (4 passes, 1.6 MB slot lines per pass fits
// every XCD L2). Edge-index re-reads are L3-resident (cheap).
// Gathers read bf16 features (half traffic); GEMMs are 4-term split-bf16
// MFMA (fp32-level accuracy); layer 2 is transform-before-aggregate.

constexpr int N_NODES = 100000;
constexpr int E_HALF  = 800000;
constexpr int CAP     = 64;
constexpr int OVF_CAP = 4096;
constexpr int NPASS   = 4;

typedef short  s16x8 __attribute__((ext_vector_type(8)));
typedef float  f32x4 __attribute__((ext_vector_type(4)));
typedef unsigned short u16;

__device__ inline float bf(u16 u) { return __uint_as_float(((unsigned)u) << 16); }
__device__ inline u16 f2bf(float v) {          // round-to-nearest-even bf16
    unsigned b = __float_as_uint(v);
    b += 0x7FFFu + ((b >> 16) & 1u);
    return (u16)(b >> 16);
}

// ------------- bucket fill, dst-partitioned: one thread per edge ----------
__global__ __launch_bounds__(256) void fill_pass_kernel(
    const int* __restrict__ ei1, const int* __restrict__ ei2,
    int* __restrict__ cnt, int* __restrict__ slots,
    int* __restrict__ ovf_cnt, int* __restrict__ ovf,
    int lo, int hi)
{
    int e = blockIdx.x * 256 + threadIdx.x;
    if (e >= 2 * E_HALF) return;
    const int* __restrict__ ei = (e < E_HALF) ? ei1 : ei2;
    int ee = (e < E_HALF) ? e : e - E_HALF;
    int dst = ei[E_HALF + ee];
    if (dst < lo || dst >= hi) return;          // other passes handle it
    int src = ei[ee];
    int pos = atomicAdd(&cnt[dst], 1);
    if (pos < CAP) {
        slots[dst * CAP + pos] = src;
    } else {
        int o = atomicAdd(ovf_cnt, 1);
        if (o < OVF_CAP) { ovf[2 * o] = src; ovf[2 * o + 1] = dst; }
    }
}

// ------------- x -> bf16 (RNE), 4 elems/thread ----------------------------
__global__ __launch_bounds__(256) void tobf16_kernel(
    const float* __restrict__ x, u16* __restrict__ xb)
{
    int i = blockIdx.x * 256 + threadIdx.x;     // N*16 threads
    if (i >= N_NODES * 16) return;
    float4 v = ((const float4*)x)[i];
    ushort4 r;
    r.x = f2bf(v.x); r.y = f2bf(v.y); r.z = f2bf(v.z); r.w = f2bf(v.w);
    ((ushort4*)xb)[i] = r;
}

// ------------- gather-mean (bf16 64-wide rows): one wave per node ---------
__global__ __launch_bounds__(256) void gather_mean_kernel(
    const u16*  __restrict__ xb,      // [N,64] bf16
    const int*  __restrict__ cnt,     // [N]
    const int*  __restrict__ slots,   // [N,CAP]
    float*      __restrict__ m)       // [N,64] mean output (fp32)
{
    int node = blockIdx.x * 4 + (threadIdx.x >> 6);
    int f    = threadIdx.x & 63;
    if (node >= N_NODES) return;
    int c  = cnt[node];
    int cc = c < CAP ? c : CAP;
    int slotv = slots[node * CAP + f];
    float a0 = 0.f, a1 = 0.f, a2 = 0.f, a3 = 0.f;
    int i = 0;
    for (; i + 8 <= cc; i += 8) {               // 8 loads in flight
        int s0 = __shfl(slotv, i),     s1 = __shfl(slotv, i + 1);
        int s2 = __shfl(slotv, i + 2), s3 = __shfl(slotv, i + 3);
        int s4 = __shfl(slotv, i + 4), s5 = __shfl(slotv, i + 5);
        int s6 = __shfl(slotv, i + 6), s7 = __shfl(slotv, i + 7);
        u16 v0 = xb[s0 * 64 + f], v1 = xb[s1 * 64 + f];
        u16 v2 = xb[s2 * 64 + f], v3 = xb[s3 * 64 + f];
        u16 v4 = xb[s4 * 64 + f], v5 = xb[s5 * 64 + f];
        u16 v6 = xb[s6 * 64 + f], v7 = xb[s7 * 64 + f];
        a0 += bf(v0) + bf(v4); a1 += bf(v1) + bf(v5);
        a2 += bf(v2) + bf(v6); a3 += bf(v3) + bf(v7);
    }
    for (; i < cc; i++) a0 += bf(xb[__shfl(slotv, i) * 64 + f]);
    float rd = 1.0f / fmaxf((float)c, 1.0f);
    m[node * 64 + f] = (a0 + a1 + a2 + a3) * rd;
}

// ------------- gather-mean (bf16 32-wide rows) + add z -> out -------------
__global__ __launch_bounds__(256) void gather_mean32_kernel(
    const u16*  __restrict__ y2b,     // [N,32] bf16 transformed features
    const float* __restrict__ z,      // [N,32] self term (bias included)
    const int*  __restrict__ cnt,
    const int*  __restrict__ slots,
    float*      __restrict__ out)     // [N,32]
{
    int node = blockIdx.x * 4 + (threadIdx.x >> 6);
    int lane = threadIdx.x & 63;
    int f    = lane & 31;
    int g    = lane >> 5;
    if (node >= N_NODES) return;
    int c  = cnt[node];
    int cc = c < CAP ? c : CAP;
    int slotv = slots[node * CAP + lane];
    float a0 = 0.f, a1 = 0.f, a2 = 0.f, a3 = 0.f;
    int i = 0;
    for (; i + 8 <= cc; i += 8) {               // 4 rows per half-wave in flight
        int sA = __shfl(slotv, i + g);
        int sB = __shfl(slotv, i + 2 + g);
        int sC = __shfl(slotv, i + 4 + g);
        int sD = __shfl(slotv, i + 6 + g);
        u16 vA = y2b[sA * 32 + f], vB = y2b[sB * 32 + f];
        u16 vC = y2b[sC * 32 + f], vD = y2b[sD * 32 + f];
        a0 += bf(vA); a1 += bf(vB); a2 += bf(vC); a3 += bf(vD);
    }
    for (; i < cc; i += 2) {
        if (i + g < cc) a0 += bf(y2b[__shfl(slotv, i + g) * 32 + f]);
    }
    float a = a0 + a1 + a2 + a3;
    a += __shfl_xor(a, 32);
    if (g == 0) {
        float rd = 1.0f / fmaxf((float)c, 1.0f);
        out[node * 32 + f] = a * rd + z[node * 32 + f];
    }
}

// ------------- overflow fallbacks (expected 0 iterations) -----------------
__global__ __launch_bounds__(256) void ovf_apply_kernel(
    const float* __restrict__ feat, const int* __restrict__ cnt,
    const int* __restrict__ ovf_cnt, const int* __restrict__ ovf,
    float* __restrict__ m)
{
    int n = *ovf_cnt;
    if (n > OVF_CAP) n = OVF_CAP;
    int total = n * 64;
    for (int t = blockIdx.x * 256 + threadIdx.x; t < total; t += gridDim.x * 256) {
        int o = t >> 6, f = t & 63;
        int src = ovf[2 * o], dst = ovf[2 * o + 1];
        float rd = 1.0f / fmaxf((float)cnt[dst], 1.0f);
        atomicAdd(&m[dst * 64 + f], feat[src * 64 + f] * rd);
    }
}

__global__ __launch_bounds__(256) void ovf_apply32_kernel(
    const u16* __restrict__ y2b, const int* __restrict__ cnt,
    const int* __restrict__ ovf_cnt, const int* __restrict__ ovf,
    float* __restrict__ out)
{
    int n = *ovf_cnt;
    if (n > OVF_CAP) n = OVF_CAP;
    int total = n * 32;
    for (int t = blockIdx.x * 256 + threadIdx.x; t < total; t += gridDim.x * 256) {
        int o = t >> 5, f = t & 31;
        int src = ovf[2 * o], dst = ovf[2 * o + 1];
        float rd = 1.0f / fmaxf((float)cnt[dst], 1.0f);
        atomicAdd(&out[dst * 32 + f], bf(y2b[src * 32 + f]) * rd);
    }
}

// ------------- hi/lo truncate-split of 8 floats to bf16 frags -------------
__device__ inline void split8(float4 v0, float4 v1, s16x8& hi, s16x8& lo) {
    float vs[8] = {v0.x, v0.y, v0.z, v0.w, v1.x, v1.y, v1.z, v1.w};
    s16x8 h, l;
    #pragma unroll
    for (int j = 0; j < 8; j++) {
        unsigned b  = __float_as_uint(vs[j]);
        float    hf = __uint_as_float(b & 0xFFFF0000u);
        float    r  = vs[j] - hf;            // exact
        h[j] = (short)(b >> 16);
        l[j] = (short)(__float_as_uint(r) >> 16);
    }
    hi = h; lo = l;
}

// ------------- weight prep ------------------------------------------------
// B1: [64,128] = [W1l|W1r] along K.  B2: [64,64] rows 0-31 = W2l, 32-63 = W2r.
__global__ __launch_bounds__(256) void wsplit_kernel(
    const float* __restrict__ W1l, const float* __restrict__ W1r,
    const float* __restrict__ W2l, const float* __restrict__ W2r,
    short* __restrict__ B1hi, short* __restrict__ B1lo,
    short* __restrict__ B2hi, short* __restrict__ B2lo)
{
    int i = blockIdx.x * 256 + threadIdx.x;
    float v; short* ph; short* pl; int idx;
    if (i < 64 * 128) {
        int o = i >> 7, k = i & 127;
        v = (k < 64) ? W1l[o * 64 + k] : W1r[o * 64 + (k - 64)];
        ph = B1hi; pl = B1lo; idx = i;
    } else if (i < 64 * 128 + 64 * 64) {
        int j = i - 64 * 128;
        int o = j >> 6, k = j & 63;
        v = (o < 32) ? W2l[o * 64 + k] : W2r[(o - 32) * 64 + k];
        ph = B2hi; pl = B2lo; idx = j;
    } else return;
    unsigned b  = __float_as_uint(v);
    float    hf = __uint_as_float(b & 0xFFFF0000u);
    float    r  = v - hf;
    ph[idx] = (short)(b >> 16);
    pl[idx] = (short)(__float_as_uint(r) >> 16);
}

// ------------- GEMM layer 1: h = relu([m|x] @ B1^T + b1), K=128 -----------
template <int MT>
__global__ __launch_bounds__(256) void gemm1_kernel(
    const float* __restrict__ Am, const float* __restrict__ Ax,
    const short* __restrict__ Bhi, const short* __restrict__ Blo,
    const float* __restrict__ bias, float* __restrict__ out)
{
    int wave = (blockIdx.x * 256 + threadIdx.x) >> 6;
    int lane = threadIdx.x & 63;
    int m0   = wave * (MT * 16);
    if (m0 >= N_NODES) return;
    int quad = lane >> 4, l16 = lane & 15;

    f32x4 acc[MT][4];
    #pragma unroll
    for (int mt = 0; mt < MT; mt++)
        #pragma unroll
        for (int nt = 0; nt < 4; nt++) acc[mt][nt] = (f32x4)0.0f;

    #pragma unroll
    for (int half = 0; half < 2; half++) {
        const float* src = half ? Ax : Am;
        #pragma unroll
        for (int sub = 0; sub < 2; sub++) {
            int kf = sub * 32 + quad * 8;
            int kc = half * 64 + sub * 32 + quad * 8;
            s16x8 ahi[MT], alo[MT];
            #pragma unroll
            for (int mt = 0; mt < MT; mt++) {
                int row = m0 + mt * 16 + l16;
                row = row < N_NODES ? row : N_NODES - 1;
                const float4* p = (const float4*)&src[row * 64 + kf];
                split8(p[0], p[1], ahi[mt], alo[mt]);
            }
            #pragma unroll
            for (int nt = 0; nt < 4; nt++) {
                int n = nt * 16 + l16;
                s16x8 bh = *(const s16x8*)&Bhi[n * 128 + kc];
                s16x8 bl = *(const s16x8*)&Blo[n * 128 + kc];
                #pragma unroll
                for (int mt = 0; mt < MT; mt++) {
                    acc[mt][nt] = __builtin_amdgcn_mfma_f32_16x16x32_bf16(ahi[mt], bh, acc[mt][nt], 0, 0, 0);
                    acc[mt][nt] = __builtin_amdgcn_mfma_f32_16x16x32_bf16(alo[mt], bh, acc[mt][nt], 0, 0, 0);
                    acc[mt][nt] = __builtin_amdgcn_mfma_f32_16x16x32_bf16(ahi[mt], bl, acc[mt][nt], 0, 0, 0);
                    acc[mt][nt] = __builtin_amdgcn_mfma_f32_16x16x32_bf16(alo[mt], bl, acc[mt][nt], 0, 0, 0);
                }
            }
        }
    }
    #pragma unroll
    for (int nt = 0; nt < 4; nt++) {
        float bv = bias[nt * 16 + l16];
        #pragma unroll
        for (int mt = 0; mt < MT; mt++)
            #pragma unroll
            for (int r = 0; r < 4; r++) {
                int row = m0 + mt * 16 + quad * 4 + r;
                if (row < N_NODES)
                    out[row * 64 + nt * 16 + l16] = fmaxf(acc[mt][nt][r] + bv, 0.0f);
            }
    }
}

// ------------- GEMM layer 2: y2b = bf16(h@W2l^T) ; z = h@W2r^T + b2 -------
template <int MT>
__global__ __launch_bounds__(256) void gemm2_kernel(
    const float* __restrict__ h,
    const short* __restrict__ Bhi, const short* __restrict__ Blo,  // [64,64]
    const float* __restrict__ b2,
    u16* __restrict__ y2b, float* __restrict__ z)                  // [N,32] each
{
    int wave = (blockIdx.x * 256 + threadIdx.x) >> 6;
    int lane = threadIdx.x & 63;
    int m0   = wave * (MT * 16);
    if (m0 >= N_NODES) return;
    int quad = lane >> 4, l16 = lane & 15;

    f32x4 acc[MT][4];
    #pragma unroll
    for (int mt = 0; mt < MT; mt++)
        #pragma unroll
        for (int nt = 0; nt < 4; nt++) acc[mt][nt] = (f32x4)0.0f;

    #pragma unroll
    for (int sub = 0; sub < 2; sub++) {
        int kf = sub * 32 + quad * 8;
        s16x8 ahi[MT], alo[MT];
        #pragma unroll
        for (int mt = 0; mt < MT; mt++) {
            int row = m0 + mt * 16 + l16;
            row = row < N_NODES ? row : N_NODES - 1;
            const float4* p = (const float4*)&h[row * 64 + kf];
            split8(p[0], p[1], ahi[mt], alo[mt]);
        }
        #pragma unroll
        for (int nt = 0; nt < 4; nt++) {
            int n = nt * 16 + l16;
            s16x8 bh = *(const s16x8*)&Bhi[n * 64 + kf];
            s16x8 bl = *(const s16x8*)&Blo[n * 64 + kf];
            #pragma unroll
            for (int mt = 0; mt < MT; mt++) {
                acc[mt][nt] = __builtin_amdgcn_mfma_f32_16x16x32_bf16(ahi[mt], bh, acc[mt][nt], 0, 0, 0);
                acc[mt][nt] = __builtin_amdgcn_mfma_f32_16x16x32_bf16(alo[mt], bh, acc[mt][nt], 0, 0, 0);
                acc[mt][nt] = __builtin_amdgcn_mfma_f32_16x16x32_bf16(ahi[mt], bl, acc[mt][nt], 0, 0, 0);
                acc[mt][nt] = __builtin_amdgcn_mfma_f32_16x16x32_bf16(alo[mt], bl, acc[mt][nt], 0, 0, 0);
            }
        }
    }
    #pragma unroll
    for (int nt = 0; nt < 4; nt++) {
        bool  isz = nt >= 2;
        int   col = (isz ? nt - 2 : nt) * 16 + l16;
        float bv  = isz ? b2[col] : 0.0f;
        #pragma unroll
        for (int mt = 0; mt < MT; mt++)
            #pragma unroll
            for (int r = 0; r < 4; r++) {
                int row = m0 + mt * 16 + quad * 4 + r;
                if (row < N_NODES) {
                    float v = acc[mt][nt][r] + bv;
                    if (isz) z[row * 32 + col] = v;
                    else     y2b[row * 32 + col] = f2bf(v);
                }
            }
    }
}

extern "C" void kernel_launch(void* const* d_in, const int* in_sizes, int n_in,
                              void* d_out, int out_size, void* d_ws, size_t ws_size,
                              hipStream_t stream) {
    const float* x   = (const float*)d_in[0];
    const int*   ei1 = (const int*)d_in[1];
    const int*   ei2 = (const int*)d_in[3];
    const float* W1l = (const float*)d_in[5];
    const float* b1  = (const float*)d_in[6];
    const float* W1r = (const float*)d_in[7];
    const float* W2l = (const float*)d_in[8];
    const float* b2  = (const float*)d_in[9];
    const float* W2r = (const float*)d_in[10];
    float* out = (float*)d_out;

    // workspace layout (256B-aligned). Aliasing plan:
    //   xb  (bf16 x, used before gemm1)   aliases h region
    //   z   (fp32, written by gemm2)      aliases m[0 : N*32 floats]
    //   y2b (bf16, written by gemm2)      aliases m[N*32 : N*48 floats]
    const size_t off_cnt    = 0;                                   // int[N]
    const size_t off_ovfcnt = 400128;
    const size_t off_ovf    = 400384;                              // int[2*OVF]
    const size_t off_slots  = 433152;                              // int[N*CAP]
    const size_t off_m      = off_slots + (size_t)N_NODES * CAP * 4;
    const size_t off_h      = off_m + (size_t)N_NODES * 64 * 4;
    const size_t off_B1hi   = off_h + (size_t)N_NODES * 64 * 4;
    const size_t off_B1lo   = off_B1hi + 64 * 128 * 2;
    const size_t off_B2hi   = off_B1lo + 64 * 128 * 2;
    const size_t off_B2lo   = off_B2hi + 64 * 64 * 2;

    char* ws = (char*)d_ws;
    int*   cnt     = (int*)(ws + off_cnt);
    int*   ovf_cnt = (int*)(ws + off_ovfcnt);
    int*   ovf     = (int*)(ws + off_ovf);
    int*   slots   = (int*)(ws + off_slots);
    float* m       = (float*)(ws + off_m);
    float* h       = (float*)(ws + off_h);
    u16*   xb      = (u16*)(ws + off_h);                           // alias h
    float* z       = (float*)(ws + off_m);                         // alias m
    u16*   y2b     = (u16*)(ws + off_m + (size_t)N_NODES * 32 * 4);// alias m
    short* B1hi    = (short*)(ws + off_B1hi);
    short* B1lo    = (short*)(ws + off_B1lo);
    short* B2hi    = (short*)(ws + off_B2hi);
    short* B2lo    = (short*)(ws + off_B2lo);

    hipMemsetAsync(ws, 0, off_slots, stream);   // cnt + ovf header only

    tobf16_kernel<<<(N_NODES * 16 + 255) / 256, 256, 0, stream>>>(x, xb);
    wsplit_kernel<<<48, 256, 0, stream>>>(
        W1l, W1r, W2l, W2r, B1hi, B1lo, B2hi, B2lo);

    // dst-partitioned fill: 4 passes, each pass's slot lines fit in L2
    {
        int blocks = (2 * E_HALF + 255) / 256;
        int span = (N_NODES + NPASS - 1) / NPASS;
        for (int p = 0; p < NPASS; p++) {
            int lo = p * span;
            int hi = lo + span < N_NODES ? lo + span : N_NODES;
            fill_pass_kernel<<<blocks, 256, 0, stream>>>(
                ei1, ei2, cnt, slots, ovf_cnt, ovf, lo, hi);
        }
    }

    // layer 1: gather-mean(bf16 x) -> m ; h = relu([m|x]@B1^T + b1)
    gather_mean_kernel<<<N_NODES / 4, 256, 0, stream>>>(xb, cnt, slots, m);
    ovf_apply_kernel<<<16, 256, 0, stream>>>(x, cnt, ovf_cnt, ovf, m);
    {
        int waves = (N_NODES + 31) / 32;   // MT=2
        gemm1_kernel<2><<<(waves + 3) / 4, 256, 0, stream>>>(
            m, x, B1hi, B1lo, b1, h);
    }

    // layer 2 (transform-first): y2b = bf16(h@W2l^T), z = h@W2r^T + b2;
    // out = gather-mean(y2b) + z
    {
        int waves = (N_NODES + 63) / 64;   // MT=4
        gemm2_kernel<4><<<(waves + 3) / 4, 256, 0, stream>>>(
            h, B2hi, B2lo, b2, y2b, z);
    }
    gather_mean32_kernel<<<N_NODES / 4, 256, 0, stream>>>(y2b, z, cnt, slots, out);
    ovf_apply32_kernel<<<16, 256, 0, stream>>>(y2b, cnt, ovf_cnt, ovf, out);
}

// Round 7
// 288.733 us; speedup vs baseline: 1.3402x; 1.1554x over previous
//
#include <hip/hip_runtime.h>

// GraphSAGE 2-layer, mean aggregation, fp32.
// R6 evidence: fill's floor is 1.6M device-scope fabric atomics on cnt
// (~20-25G random req/s), not store bytes. Fix: two-phase binning build —
// pass A bins edges into 200 dst-buckets (LDS histogram, 1 fabric atomic
// per block per bucket = 39K total), pass B builds slots per-bucket with
// LDS counters (0 fabric atomics, L2-resident 125KB slot window).
// Gathers: ushort4 wide loads (4 rows/instr for 64-wide, 8 for 32-wide),
// shfl_xor reduce, conditional slot read. GEMMs: 4-term split-bf16 MFMA.

constexpr int N_NODES = 100000;
constexpr int E_HALF  = 800000;
constexpr int E_TOT   = 2 * E_HALF;
constexpr int CAP     = 64;      // slots per node
constexpr int OVF_CAP = 4096;    // overflow capacity (expected use: 0)
constexpr int NB      = 200;     // coarse buckets
constexpr int NPB     = 500;     // nodes per bucket
constexpr int BCAP    = 12288;   // edges per bucket (mean 8000, +48 sigma)
constexpr int EPB_A   = 8192;    // edges per pass-A block

typedef short  s16x8 __attribute__((ext_vector_type(8)));
typedef float  f32x4 __attribute__((ext_vector_type(4)));
typedef unsigned short u16;

__device__ inline float bf(u16 u) { return __uint_as_float(((unsigned)u) << 16); }
__device__ inline u16 f2bf(float v) {          // round-to-nearest-even bf16
    unsigned b = __float_as_uint(v);
    b += 0x7FFFu + ((b >> 16) & 1u);
    return (u16)(b >> 16);
}

// ------------- pass A: bin edges into 200 coarse dst-buckets --------------
__global__ __launch_bounds__(256) void binA_kernel(
    const int* __restrict__ ei1, const int* __restrict__ ei2,
    uint2* __restrict__ barr, int* __restrict__ bcur,
    int* __restrict__ ovfA_cnt, int* __restrict__ ovfA)
{
    __shared__ int hist[NB], base[NB], cur[NB];
    int tid = threadIdx.x;
    for (int t = tid; t < NB; t += 256) { hist[t] = 0; cur[t] = 0; }
    __syncthreads();
    int e0 = blockIdx.x * EPB_A;
    #pragma unroll 4
    for (int k = 0; k < EPB_A / 256; k++) {
        int e = e0 + k * 256 + tid;
        if (e >= E_TOT) break;
        const int* ei = (e < E_HALF) ? ei1 : ei2;
        int ee = (e < E_HALF) ? e : e - E_HALF;
        int dst = ei[E_HALF + ee];
        atomicAdd(&hist[dst / NPB], 1);
    }
    __syncthreads();
    for (int t = tid; t < NB; t += 256)
        base[t] = atomicAdd(&bcur[t], hist[t]);   // 200 fabric atomics/block
    __syncthreads();
    #pragma unroll 4
    for (int k = 0; k < EPB_A / 256; k++) {
        int e = e0 + k * 256 + tid;
        if (e >= E_TOT) break;
        const int* ei = (e < E_HALF) ? ei1 : ei2;
        int ee = (e < E_HALF) ? e : e - E_HALF;
        int dst = ei[E_HALF + ee];
        int src = ei[ee];
        int b   = dst / NPB;
        int pos = base[b] + atomicAdd(&cur[b], 1);
        if (pos < BCAP) {
            barr[b * BCAP + pos] = make_uint2((unsigned)src, (unsigned)dst);
        } else {
            int o = atomicAdd(ovfA_cnt, 1);
            if (o < OVF_CAP) { ovfA[2 * o] = src; ovfA[2 * o + 1] = dst; }
        }
    }
}

// ------------- pass B: per-bucket slot build with LDS counters ------------
__global__ __launch_bounds__(256) void binB_kernel(
    const uint2* __restrict__ barr, const int* __restrict__ bcur,
    int* __restrict__ cnt, int* __restrict__ slots,
    int* __restrict__ ovfB_cnt, int* __restrict__ ovfB)
{
    __shared__ int lcnt[NPB];
    int tid = threadIdx.x, b = blockIdx.x;
    for (int t = tid; t < NPB; t += 256) lcnt[t] = 0;
    __syncthreads();
    int nE = bcur[b]; if (nE > BCAP) nE = BCAP;
    int dbase = b * NPB;
    for (int i = tid; i < nE; i += 256) {
        uint2 e = barr[b * BCAP + i];
        int dst = (int)e.y;
        int pos = atomicAdd(&lcnt[dst - dbase], 1);   // LDS atomic
        if (pos < CAP) {
            slots[dst * CAP + pos] = (int)e.x;        // L2-resident window
        } else {
            int o = atomicAdd(ovfB_cnt, 1);
            if (o < OVF_CAP) { ovfB[2 * o] = (int)e.x; ovfB[2 * o + 1] = dst; }
        }
    }
    __syncthreads();
    for (int t = tid; t < NPB; t += 256) {
        int n = dbase + t;
        if (n < N_NODES) cnt[n] = lcnt[t];
    }
}

// ------------- cnt fix for pass-A overflow edges (expected 0) -------------
__global__ __launch_bounds__(256) void ovf_fix_kernel(
    const int* __restrict__ ovfA_cnt, const int* __restrict__ ovfA,
    int* __restrict__ cnt)
{
    int n = *ovfA_cnt; if (n > OVF_CAP) n = OVF_CAP;
    int t = blockIdx.x * 256 + threadIdx.x;
    if (t < n) atomicAdd(&cnt[ovfA[2 * t + 1]], 1);
}

// ------------- x -> bf16 (RNE), 4 elems/thread ----------------------------
__global__ __launch_bounds__(256) void tobf16_kernel(
    const float* __restrict__ x, u16* __restrict__ xb)
{
    int i = blockIdx.x * 256 + threadIdx.x;     // N*16 threads
    if (i >= N_NODES * 16) return;
    float4 v = ((const float4*)x)[i];
    ushort4 r;
    r.x = f2bf(v.x); r.y = f2bf(v.y); r.z = f2bf(v.z); r.w = f2bf(v.w);
    ((ushort4*)xb)[i] = r;
}

// ------------- gather-mean 64-wide: wave/node, 4 rows per load-instr ------
__global__ __launch_bounds__(256) void gather_mean_kernel(
    const u16*  __restrict__ xb,      // [N,64] bf16
    const int*  __restrict__ cnt,     // [N]
    const int*  __restrict__ slots,   // [N,CAP]
    float*      __restrict__ m)       // [N,64] mean (fp32)
{
    int node = blockIdx.x * 4 + (threadIdx.x >> 6);
    int lane = threadIdx.x & 63;
    int r    = lane >> 4;             // row subgroup 0..3
    int c    = lane & 15;             // feature block (4 feats)
    if (node >= N_NODES) return;
    int cdeg = cnt[node];
    int cc   = cdeg < CAP ? cdeg : CAP;
    int slotv = (lane < cc) ? slots[node * CAP + lane] : 0;  // only live lines
    float a0 = 0.f, a1 = 0.f, a2 = 0.f, a3 = 0.f;
    for (int i = 0; i < cc; i += 4) {
        int idx = i + r;
        int s = __shfl(slotv, idx < 63 ? idx : 63);
        if (idx < cc) {
            ushort4 v = *(const ushort4*)&xb[s * 64 + c * 4];  // 8B/lane
            a0 += bf(v.x); a1 += bf(v.y); a2 += bf(v.z); a3 += bf(v.w);
        }
    }
    a0 += __shfl_xor(a0, 16); a0 += __shfl_xor(a0, 32);
    a1 += __shfl_xor(a1, 16); a1 += __shfl_xor(a1, 32);
    a2 += __shfl_xor(a2, 16); a2 += __shfl_xor(a2, 32);
    a3 += __shfl_xor(a3, 16); a3 += __shfl_xor(a3, 32);
    if (r == 0) {
        float rd = 1.0f / fmaxf((float)cdeg, 1.0f);
        *(float4*)&m[node * 64 + c * 4] =
            make_float4(a0 * rd, a1 * rd, a2 * rd, a3 * rd);
    }
}

// ------------- gather-mean 32-wide + add z -> out, 8 rows per instr -------
__global__ __launch_bounds__(256) void gather_mean32_kernel(
    const u16*  __restrict__ y2b,     // [N,32] bf16
    const float* __restrict__ z,      // [N,32] self term (bias included)
    const int*  __restrict__ cnt,
    const int*  __restrict__ slots,
    float*      __restrict__ out)     // [N,32]
{
    int node = blockIdx.x * 4 + (threadIdx.x >> 6);
    int lane = threadIdx.x & 63;
    int r    = lane >> 3;             // row subgroup 0..7
    int c    = lane & 7;              // feature block (4 feats)
    if (node >= N_NODES) return;
    int cdeg = cnt[node];
    int cc   = cdeg < CAP ? cdeg : CAP;
    int slotv = (lane < cc) ? slots[node * CAP + lane] : 0;
    float a0 = 0.f, a1 = 0.f, a2 = 0.f, a3 = 0.f;
    for (int i = 0; i < cc; i += 8) {
        int idx = i + r;
        int s = __shfl(slotv, idx < 63 ? idx : 63);
        if (idx < cc) {
            ushort4 v = *(const ushort4*)&y2b[s * 32 + c * 4];
            a0 += bf(v.x); a1 += bf(v.y); a2 += bf(v.z); a3 += bf(v.w);
        }
    }
    a0 += __shfl_xor(a0, 8); a0 += __shfl_xor(a0, 16); a0 += __shfl_xor(a0, 32);
    a1 += __shfl_xor(a1, 8); a1 += __shfl_xor(a1, 16); a1 += __shfl_xor(a1, 32);
    a2 += __shfl_xor(a2, 8); a2 += __shfl_xor(a2, 16); a2 += __shfl_xor(a2, 32);
    a3 += __shfl_xor(a3, 8); a3 += __shfl_xor(a3, 16); a3 += __shfl_xor(a3, 32);
    if (r == 0) {
        float rd = 1.0f / fmaxf((float)cdeg, 1.0f);
        float4 zz = *(const float4*)&z[node * 32 + c * 4];
        *(float4*)&out[node * 32 + c * 4] = make_float4(
            a0 * rd + zz.x, a1 * rd + zz.y, a2 * rd + zz.z, a3 * rd + zz.w);
    }
}

// ------------- overflow apply (dual list, expected 0 iterations) ----------
__global__ __launch_bounds__(256) void ovf_apply_kernel(
    const float* __restrict__ feat, const int* __restrict__ cnt,
    const int* __restrict__ ovfA_cnt, const int* __restrict__ ovfA,
    const int* __restrict__ ovfB_cnt, const int* __restrict__ ovfB,
    float* __restrict__ m)
{
    int nA = *ovfA_cnt; if (nA > OVF_CAP) nA = OVF_CAP;
    int nB = *ovfB_cnt; if (nB > OVF_CAP) nB = OVF_CAP;
    int total = (nA + nB) * 64;
    for (int t = blockIdx.x * 256 + threadIdx.x; t < total; t += gridDim.x * 256) {
        int o = t >> 6, f = t & 63;
        const int* L = (o < nA) ? &ovfA[2 * o] : &ovfB[2 * (o - nA)];
        int src = L[0], dst = L[1];
        float rd = 1.0f / fmaxf((float)cnt[dst], 1.0f);
        atomicAdd(&m[dst * 64 + f], feat[src * 64 + f] * rd);
    }
}

__global__ __launch_bounds__(256) void ovf_apply32_kernel(
    const u16* __restrict__ y2b, const int* __restrict__ cnt,
    const int* __restrict__ ovfA_cnt, const int* __restrict__ ovfA,
    const int* __restrict__ ovfB_cnt, const int* __restrict__ ovfB,
    float* __restrict__ out)
{
    int nA = *ovfA_cnt; if (nA > OVF_CAP) nA = OVF_CAP;
    int nB = *ovfB_cnt; if (nB > OVF_CAP) nB = OVF_CAP;
    int total = (nA + nB) * 32;
    for (int t = blockIdx.x * 256 + threadIdx.x; t < total; t += gridDim.x * 256) {
        int o = t >> 5, f = t & 31;
        const int* L = (o < nA) ? &ovfA[2 * o] : &ovfB[2 * (o - nA)];
        int src = L[0], dst = L[1];
        float rd = 1.0f / fmaxf((float)cnt[dst], 1.0f);
        atomicAdd(&out[dst * 32 + f], bf(y2b[src * 32 + f]) * rd);
    }
}

// ------------- hi/lo truncate-split of 8 floats to bf16 frags -------------
__device__ inline void split8(float4 v0, float4 v1, s16x8& hi, s16x8& lo) {
    float vs[8] = {v0.x, v0.y, v0.z, v0.w, v1.x, v1.y, v1.z, v1.w};
    s16x8 h, l;
    #pragma unroll
    for (int j = 0; j < 8; j++) {
        unsigned b  = __float_as_uint(vs[j]);
        float    hf = __uint_as_float(b & 0xFFFF0000u);
        float    r  = vs[j] - hf;            // exact
        h[j] = (short)(b >> 16);
        l[j] = (short)(__float_as_uint(r) >> 16);
    }
    hi = h; lo = l;
}

// ------------- weight prep ------------------------------------------------
__global__ __launch_bounds__(256) void wsplit_kernel(
    const float* __restrict__ W1l, const float* __restrict__ W1r,
    const float* __restrict__ W2l, const float* __restrict__ W2r,
    short* __restrict__ B1hi, short* __restrict__ B1lo,
    short* __restrict__ B2hi, short* __restrict__ B2lo)
{
    int i = blockIdx.x * 256 + threadIdx.x;
    float v; short* ph; short* pl; int idx;
    if (i < 64 * 128) {
        int o = i >> 7, k = i & 127;
        v = (k < 64) ? W1l[o * 64 + k] : W1r[o * 64 + (k - 64)];
        ph = B1hi; pl = B1lo; idx = i;
    } else if (i < 64 * 128 + 64 * 64) {
        int j = i - 64 * 128;
        int o = j >> 6, k = j & 63;
        v = (o < 32) ? W2l[o * 64 + k] : W2r[(o - 32) * 64 + k];
        ph = B2hi; pl = B2lo; idx = j;
    } else return;
    unsigned b  = __float_as_uint(v);
    float    hf = __uint_as_float(b & 0xFFFF0000u);
    float    r  = v - hf;
    ph[idx] = (short)(b >> 16);
    pl[idx] = (short)(__float_as_uint(r) >> 16);
}

// ------------- GEMM layer 1: h = relu([m|x] @ B1^T + b1), K=128 -----------
template <int MT>
__global__ __launch_bounds__(256) void gemm1_kernel(
    const float* __restrict__ Am, const float* __restrict__ Ax,
    const short* __restrict__ Bhi, const short* __restrict__ Blo,
    const float* __restrict__ bias, float* __restrict__ out)
{
    int wave = (blockIdx.x * 256 + threadIdx.x) >> 6;
    int lane = threadIdx.x & 63;
    int m0   = wave * (MT * 16);
    if (m0 >= N_NODES) return;
    int quad = lane >> 4, l16 = lane & 15;

    f32x4 acc[MT][4];
    #pragma unroll
    for (int mt = 0; mt < MT; mt++)
        #pragma unroll
        for (int nt = 0; nt < 4; nt++) acc[mt][nt] = (f32x4)0.0f;

    #pragma unroll
    for (int half = 0; half < 2; half++) {
        const float* src = half ? Ax : Am;
        #pragma unroll
        for (int sub = 0; sub < 2; sub++) {
            int kf = sub * 32 + quad * 8;
            int kc = half * 64 + sub * 32 + quad * 8;
            s16x8 ahi[MT], alo[MT];
            #pragma unroll
            for (int mt = 0; mt < MT; mt++) {
                int row = m0 + mt * 16 + l16;
                row = row < N_NODES ? row : N_NODES - 1;
                const float4* p = (const float4*)&src[row * 64 + kf];
                split8(p[0], p[1], ahi[mt], alo[mt]);
            }
            #pragma unroll
            for (int nt = 0; nt < 4; nt++) {
                int n = nt * 16 + l16;
                s16x8 bh = *(const s16x8*)&Bhi[n * 128 + kc];
                s16x8 bl = *(const s16x8*)&Blo[n * 128 + kc];
                #pragma unroll
                for (int mt = 0; mt < MT; mt++) {
                    acc[mt][nt] = __builtin_amdgcn_mfma_f32_16x16x32_bf16(ahi[mt], bh, acc[mt][nt], 0, 0, 0);
                    acc[mt][nt] = __builtin_amdgcn_mfma_f32_16x16x32_bf16(alo[mt], bh, acc[mt][nt], 0, 0, 0);
                    acc[mt][nt] = __builtin_amdgcn_mfma_f32_16x16x32_bf16(ahi[mt], bl, acc[mt][nt], 0, 0, 0);
                    acc[mt][nt] = __builtin_amdgcn_mfma_f32_16x16x32_bf16(alo[mt], bl, acc[mt][nt], 0, 0, 0);
                }
            }
        }
    }
    #pragma unroll
    for (int nt = 0; nt < 4; nt++) {
        float bv = bias[nt * 16 + l16];
        #pragma unroll
        for (int mt = 0; mt < MT; mt++)
            #pragma unroll
            for (int r = 0; r < 4; r++) {
                int row = m0 + mt * 16 + quad * 4 + r;
                if (row < N_NODES)
                    out[row * 64 + nt * 16 + l16] = fmaxf(acc[mt][nt][r] + bv, 0.0f);
            }
    }
}

// ------------- GEMM layer 2: y2b = bf16(h@W2l^T) ; z = h@W2r^T + b2 -------
template <int MT>
__global__ __launch_bounds__(256) void gemm2_kernel(
    const float* __restrict__ h,
    const short* __restrict__ Bhi, const short* __restrict__ Blo,  // [64,64]
    const float* __restrict__ b2,
    u16* __restrict__ y2b, float* __restrict__ z)                  // [N,32] each
{
    int wave = (blockIdx.x * 256 + threadIdx.x) >> 6;
    int lane = threadIdx.x & 63;
    int m0   = wave * (MT * 16);
    if (m0 >= N_NODES) return;
    int quad = lane >> 4, l16 = lane & 15;

    f32x4 acc[MT][4];
    #pragma unroll
    for (int mt = 0; mt < MT; mt++)
        #pragma unroll
        for (int nt = 0; nt < 4; nt++) acc[mt][nt] = (f32x4)0.0f;

    #pragma unroll
    for (int sub = 0; sub < 2; sub++) {
        int kf = sub * 32 + quad * 8;
        s16x8 ahi[MT], alo[MT];
        #pragma unroll
        for (int mt = 0; mt < MT; mt++) {
            int row = m0 + mt * 16 + l16;
            row = row < N_NODES ? row : N_NODES - 1;
            const float4* p = (const float4*)&h[row * 64 + kf];
            split8(p[0], p[1], ahi[mt], alo[mt]);
        }
        #pragma unroll
        for (int nt = 0; nt < 4; nt++) {
            int n = nt * 16 + l16;
            s16x8 bh = *(const s16x8*)&Bhi[n * 64 + kf];
            s16x8 bl = *(const s16x8*)&Blo[n * 64 + kf];
            #pragma unroll
            for (int mt = 0; mt < MT; mt++) {
                acc[mt][nt] = __builtin_amdgcn_mfma_f32_16x16x32_bf16(ahi[mt], bh, acc[mt][nt], 0, 0, 0);
                acc[mt][nt] = __builtin_amdgcn_mfma_f32_16x16x32_bf16(alo[mt], bh, acc[mt][nt], 0, 0, 0);
                acc[mt][nt] = __builtin_amdgcn_mfma_f32_16x16x32_bf16(ahi[mt], bl, acc[mt][nt], 0, 0, 0);
                acc[mt][nt] = __builtin_amdgcn_mfma_f32_16x16x32_bf16(alo[mt], bl, acc[mt][nt], 0, 0, 0);
            }
        }
    }
    #pragma unroll
    for (int nt = 0; nt < 4; nt++) {
        bool  isz = nt >= 2;
        int   col = (isz ? nt - 2 : nt) * 16 + l16;
        float bv  = isz ? b2[col] : 0.0f;
        #pragma unroll
        for (int mt = 0; mt < MT; mt++)
            #pragma unroll
            for (int r = 0; r < 4; r++) {
                int row = m0 + mt * 16 + quad * 4 + r;
                if (row < N_NODES) {
                    float v = acc[mt][nt][r] + bv;
                    if (isz) z[row * 32 + col] = v;
                    else     y2b[row * 32 + col] = f2bf(v);
                }
            }
    }
}

extern "C" void kernel_launch(void* const* d_in, const int* in_sizes, int n_in,
                              void* d_out, int out_size, void* d_ws, size_t ws_size,
                              hipStream_t stream) {
    const float* x   = (const float*)d_in[0];
    const int*   ei1 = (const int*)d_in[1];
    const int*   ei2 = (const int*)d_in[3];
    const float* W1l = (const float*)d_in[5];
    const float* b1  = (const float*)d_in[6];
    const float* W1r = (const float*)d_in[7];
    const float* W2l = (const float*)d_in[8];
    const float* b2  = (const float*)d_in[9];
    const float* W2r = (const float*)d_in[10];
    float* out = (float*)d_out;

    // workspace layout. Aliases: barr -> m region (dead before gather writes
    // m); z/y2b -> m region (dead after gemm1); xb -> h region (dead before
    // gemm1 writes h).
    const size_t off_cnt   = 0;                                    // int[N]
    const size_t off_misc  = 400128;
    const size_t off_ovfAc = off_misc + 0;
    const size_t off_ovfBc = off_misc + 4;
    const size_t off_bcur  = off_misc + 256;                       // int[NB]
    const size_t off_ovfA  = off_misc + 1280;                      // 32 KB
    const size_t off_ovfB  = off_misc + 1280 + 8 * OVF_CAP;        // 32 KB
    const size_t off_slots = 467200;                               // int[N*CAP]
    const size_t off_m     = off_slots + (size_t)N_NODES * CAP * 4;
    const size_t off_h     = off_m + (size_t)N_NODES * 64 * 4;
    const size_t off_B1hi  = off_h + (size_t)N_NODES * 64 * 4;
    const size_t off_B1lo  = off_B1hi + 64 * 128 * 2;
    const size_t off_B2hi  = off_B1lo + 64 * 128 * 2;
    const size_t off_B2lo  = off_B2hi + 64 * 64 * 2;

    char* ws = (char*)d_ws;
    int*   cnt     = (int*)(ws + off_cnt);
    int*   ovfA_c  = (int*)(ws + off_ovfAc);
    int*   ovfB_c  = (int*)(ws + off_ovfBc);
    int*   bcur    = (int*)(ws + off_bcur);
    int*   ovfA    = (int*)(ws + off_ovfA);
    int*   ovfB    = (int*)(ws + off_ovfB);
    int*   slots   = (int*)(ws + off_slots);
    uint2* barr    = (uint2*)(ws + off_m);                         // alias m
    float* m       = (float*)(ws + off_m);
    float* h       = (float*)(ws + off_h);
    u16*   xb      = (u16*)(ws + off_h);                           // alias h
    float* z       = (float*)(ws + off_m);                         // alias m
    u16*   y2b     = (u16*)(ws + off_m + (size_t)N_NODES * 32 * 4);// alias m
    short* B1hi    = (short*)(ws + off_B1hi);
    short* B1lo    = (short*)(ws + off_B1lo);
    short* B2hi    = (short*)(ws + off_B2hi);
    short* B2lo    = (short*)(ws + off_B2lo);

    // zero only counters + bucket cursors + ovf lists (~67 KB)
    hipMemsetAsync(ws + off_misc, 0, off_slots - off_misc, stream);

    tobf16_kernel<<<(N_NODES * 16 + 255) / 256, 256, 0, stream>>>(x, xb);
    wsplit_kernel<<<48, 256, 0, stream>>>(
        W1l, W1r, W2l, W2r, B1hi, B1lo, B2hi, B2lo);

    // binning build (shared by both layers)
    binA_kernel<<<(E_TOT + EPB_A - 1) / EPB_A, 256, 0, stream>>>(
        ei1, ei2, barr, bcur, ovfA_c, ovfA);
    binB_kernel<<<NB, 256, 0, stream>>>(barr, bcur, cnt, slots, ovfB_c, ovfB);
    ovf_fix_kernel<<<OVF_CAP / 256, 256, 0, stream>>>(ovfA_c, ovfA, cnt);

    // layer 1: gather-mean(bf16 x) -> m ; h = relu([m|x]@B1^T + b1)
    gather_mean_kernel<<<N_NODES / 4, 256, 0, stream>>>(xb, cnt, slots, m);
    ovf_apply_kernel<<<16, 256, 0, stream>>>(
        x, cnt, ovfA_c, ovfA, ovfB_c, ovfB, m);
    {
        int waves = (N_NODES + 31) / 32;   // MT=2
        gemm1_kernel<2><<<(waves + 3) / 4, 256, 0, stream>>>(
            m, x, B1hi, B1lo, b1, h);
    }

    // layer 2 (transform-first): y2b = bf16(h@W2l^T), z = h@W2r^T + b2;
    // out = gather-mean(y2b) + z
    {
        int waves = (N_NODES + 63) / 64;   // MT=4
        gemm2_kernel<4><<<(waves + 3) / 4, 256, 0, stream>>>(
            h, B2hi, B2lo, b2, y2b, z);
    }
    gather_mean32_kernel<<<N_NODES / 4, 256, 0, stream>>>(y2b, z, cnt, slots, out);
    ovf_apply32_kernel<<<16, 256, 0, stream>>>(
        y2b, cnt, ovfA_c, ovfA, ovfB_c, ovfB, out);
}

// Round 10
// 277.995 us; speedup vs baseline: 1.3920x; 1.0386x over previous
//
#include <hip/hip_runtime.h>

// GraphSAGE 2-layer, mean aggregation, fp32.
// R8/R9 (fused LDS-atomic aggregation) failed correctness twice with an
// unexplained ~0.06 structural error; reverted to the R7 structure (proven:
// 289 us, absmax 7.8e-3). R10 = R7 + (a) 2-deep load ILP in both gathers
// (independent masked loads, zero-init exact), (b) tobf16+wsplit merged
// into one prep kernel. All else identical to R7.

constexpr int N_NODES = 100000;
constexpr int E_HALF  = 800000;
constexpr int E_TOT   = 2 * E_HALF;
constexpr int CAP     = 64;      // slots per node
constexpr int OVF_CAP = 4096;    // overflow capacity (expected use: 0)
constexpr int NB      = 200;     // coarse buckets
constexpr int NPB     = 500;     // nodes per bucket
constexpr int BCAP    = 12288;   // edges per bucket (mean 8000, +48 sigma)
constexpr int EPB_A   = 8192;    // edges per pass-A block

typedef short  s16x8 __attribute__((ext_vector_type(8)));
typedef float  f32x4 __attribute__((ext_vector_type(4)));
typedef unsigned short u16;

__device__ inline float bf(u16 u) { return __uint_as_float(((unsigned)u) << 16); }
__device__ inline u16 f2bf(float v) {          // round-to-nearest-even bf16
    unsigned b = __float_as_uint(v);
    b += 0x7FFFu + ((b >> 16) & 1u);
    return (u16)(b >> 16);
}

// ------------- pass A: bin edges into 200 coarse dst-buckets --------------
__global__ __launch_bounds__(256) void binA_kernel(
    const int* __restrict__ ei1, const int* __restrict__ ei2,
    uint2* __restrict__ barr, int* __restrict__ bcur,
    int* __restrict__ ovfA_cnt, int* __restrict__ ovfA)
{
    __shared__ int hist[NB], base[NB], cur[NB];
    int tid = threadIdx.x;
    for (int t = tid; t < NB; t += 256) { hist[t] = 0; cur[t] = 0; }
    __syncthreads();
    int e0 = blockIdx.x * EPB_A;
    #pragma unroll 4
    for (int k = 0; k < EPB_A / 256; k++) {
        int e = e0 + k * 256 + tid;
        if (e >= E_TOT) break;
        const int* ei = (e < E_HALF) ? ei1 : ei2;
        int ee = (e < E_HALF) ? e : e - E_HALF;
        int dst = ei[E_HALF + ee];
        atomicAdd(&hist[dst / NPB], 1);
    }
    __syncthreads();
    for (int t = tid; t < NB; t += 256)
        base[t] = atomicAdd(&bcur[t], hist[t]);   // 200 fabric atomics/block
    __syncthreads();
    #pragma unroll 4
    for (int k = 0; k < EPB_A / 256; k++) {
        int e = e0 + k * 256 + tid;
        if (e >= E_TOT) break;
        const int* ei = (e < E_HALF) ? ei1 : ei2;
        int ee = (e < E_HALF) ? e : e - E_HALF;
        int dst = ei[E_HALF + ee];
        int src = ei[ee];
        int b   = dst / NPB;
        int pos = base[b] + atomicAdd(&cur[b], 1);
        if (pos < BCAP) {
            barr[b * BCAP + pos] = make_uint2((unsigned)src, (unsigned)dst);
        } else {
            int o = atomicAdd(ovfA_cnt, 1);
            if (o < OVF_CAP) { ovfA[2 * o] = src; ovfA[2 * o + 1] = dst; }
        }
    }
}

// ------------- pass B: per-bucket slot build with LDS counters ------------
__global__ __launch_bounds__(256) void binB_kernel(
    const uint2* __restrict__ barr, const int* __restrict__ bcur,
    int* __restrict__ cnt, int* __restrict__ slots,
    int* __restrict__ ovfB_cnt, int* __restrict__ ovfB)
{
    __shared__ int lcnt[NPB];
    int tid = threadIdx.x, b = blockIdx.x;
    for (int t = tid; t < NPB; t += 256) lcnt[t] = 0;
    __syncthreads();
    int nE = bcur[b]; if (nE > BCAP) nE = BCAP;
    int dbase = b * NPB;
    for (int i = tid; i < nE; i += 256) {
        uint2 e = barr[b * BCAP + i];
        int dst = (int)e.y;
        int pos = atomicAdd(&lcnt[dst - dbase], 1);   // LDS atomic
        if (pos < CAP) {
            slots[dst * CAP + pos] = (int)e.x;        // L2-resident window
        } else {
            int o = atomicAdd(ovfB_cnt, 1);
            if (o < OVF_CAP) { ovfB[2 * o] = (int)e.x; ovfB[2 * o + 1] = dst; }
        }
    }
    __syncthreads();
    for (int t = tid; t < NPB; t += 256) {
        int n = dbase + t;
        if (n < N_NODES) cnt[n] = lcnt[t];
    }
}

// ------------- cnt fix for pass-A overflow edges (expected 0) -------------
__global__ __launch_bounds__(256) void ovf_fix_kernel(
    const int* __restrict__ ovfA_cnt, const int* __restrict__ ovfA,
    int* __restrict__ cnt)
{
    int n = *ovfA_cnt; if (n > OVF_CAP) n = OVF_CAP;
    int t = blockIdx.x * 256 + threadIdx.x;
    if (t < n) atomicAdd(&cnt[ovfA[2 * t + 1]], 1);
}

// ------------- prep: x -> bf16 (blocks 0..6249) + weight split (48) -------
__global__ __launch_bounds__(256) void prep_kernel(
    const float* __restrict__ x, u16* __restrict__ xb,
    const float* __restrict__ W1l, const float* __restrict__ W1r,
    const float* __restrict__ W2l, const float* __restrict__ W2r,
    short* __restrict__ B1hi, short* __restrict__ B1lo,
    short* __restrict__ B2hi, short* __restrict__ B2lo)
{
    int blk = blockIdx.x;
    if (blk < 6250) {                        // N*16 float4 = 6250*256 exact
        int i = blk * 256 + threadIdx.x;
        float4 v = ((const float4*)x)[i];
        ushort4 rr;
        rr.x = f2bf(v.x); rr.y = f2bf(v.y); rr.z = f2bf(v.z); rr.w = f2bf(v.w);
        ((ushort4*)xb)[i] = rr;
        return;
    }
    int i = (blk - 6250) * 256 + threadIdx.x;   // 48*256 = 12288 exact
    float v; short* ph; short* pl; int idx;
    if (i < 64 * 128) {
        int o = i >> 7, k = i & 127;
        v = (k < 64) ? W1l[o * 64 + k] : W1r[o * 64 + (k - 64)];
        ph = B1hi; pl = B1lo; idx = i;
    } else {
        int j = i - 64 * 128;                   // j < 64*64
        int o = j >> 6, k = j & 63;
        v = (o < 32) ? W2l[o * 64 + k] : W2r[(o - 32) * 64 + k];
        ph = B2hi; pl = B2lo; idx = j;
    }
    unsigned b  = __float_as_uint(v);
    float    hf = __uint_as_float(b & 0xFFFF0000u);
    float    r  = v - hf;
    ph[idx] = (short)(b >> 16);
    pl[idx] = (short)(__float_as_uint(r) >> 16);
}

// ------------- gather-mean 64-wide: wave/node, 2 loads/lane in flight -----
__global__ __launch_bounds__(256) void gather_mean_kernel(
    const u16*  __restrict__ xb,      // [N,64] bf16
    const int*  __restrict__ cnt,     // [N]
    const int*  __restrict__ slots,   // [N,CAP]
    float*      __restrict__ m)       // [N,64] mean (fp32)
{
    int node = blockIdx.x * 4 + (threadIdx.x >> 6);
    int lane = threadIdx.x & 63;
    int r    = lane >> 4;             // row subgroup 0..3
    int c    = lane & 15;             // feature block (4 feats)
    if (node >= N_NODES) return;
    int cdeg = cnt[node];
    int cc   = cdeg < CAP ? cdeg : CAP;
    int slotv = (lane < cc) ? slots[node * CAP + lane] : 0;
    float a0 = 0.f, a1 = 0.f, a2 = 0.f, a3 = 0.f;
    float b0 = 0.f, b1 = 0.f, b2 = 0.f, b3 = 0.f;
    for (int i = 0; i < cc; i += 8) {
        int iA = i + r, iB = i + 4 + r;
        int sA = __shfl(slotv, iA & 63);
        int sB = __shfl(slotv, iB & 63);
        ushort4 vA = make_ushort4(0, 0, 0, 0);
        ushort4 vB = make_ushort4(0, 0, 0, 0);
        if (iA < cc) vA = *(const ushort4*)&xb[sA * 64 + c * 4];
        if (iB < cc) vB = *(const ushort4*)&xb[sB * 64 + c * 4];
        a0 += bf(vA.x); a1 += bf(vA.y); a2 += bf(vA.z); a3 += bf(vA.w);
        b0 += bf(vB.x); b1 += bf(vB.y); b2 += bf(vB.z); b3 += bf(vB.w);
    }
    a0 += b0; a1 += b1; a2 += b2; a3 += b3;
    a0 += __shfl_xor(a0, 16); a0 += __shfl_xor(a0, 32);
    a1 += __shfl_xor(a1, 16); a1 += __shfl_xor(a1, 32);
    a2 += __shfl_xor(a2, 16); a2 += __shfl_xor(a2, 32);
    a3 += __shfl_xor(a3, 16); a3 += __shfl_xor(a3, 32);
    if (r == 0) {
        float rd = 1.0f / fmaxf((float)cdeg, 1.0f);
        *(float4*)&m[node * 64 + c * 4] =
            make_float4(a0 * rd, a1 * rd, a2 * rd, a3 * rd);
    }
}

// ------------- gather-mean 32-wide + add z -> out, 2 loads/lane -----------
__global__ __launch_bounds__(256) void gather_mean32_kernel(
    const u16*  __restrict__ y2b,     // [N,32] bf16
    const float* __restrict__ z,      // [N,32] self term (bias included)
    const int*  __restrict__ cnt,
    const int*  __restrict__ slots,
    float*      __restrict__ out)     // [N,32]
{
    int node = blockIdx.x * 4 + (threadIdx.x >> 6);
    int lane = threadIdx.x & 63;
    int r    = lane >> 3;             // row subgroup 0..7
    int c    = lane & 7;              // feature block (4 feats)
    if (node >= N_NODES) return;
    int cdeg = cnt[node];
    int cc   = cdeg < CAP ? cdeg : CAP;
    int slotv = (lane < cc) ? slots[node * CAP + lane] : 0;
    float a0 = 0.f, a1 = 0.f, a2 = 0.f, a3 = 0.f;
    float b0 = 0.f, b1 = 0.f, b2 = 0.f, b3 = 0.f;
    for (int i = 0; i < cc; i += 16) {
        int iA = i + r, iB = i + 8 + r;
        int sA = __shfl(slotv, iA & 63);
        int sB = __shfl(slotv, iB & 63);
        ushort4 vA = make_ushort4(0, 0, 0, 0);
        ushort4 vB = make_ushort4(0, 0, 0, 0);
        if (iA < cc) vA = *(const ushort4*)&y2b[sA * 32 + c * 4];
        if (iB < cc) vB = *(const ushort4*)&y2b[sB * 32 + c * 4];
        a0 += bf(vA.x); a1 += bf(vA.y); a2 += bf(vA.z); a3 += bf(vA.w);
        b0 += bf(vB.x); b1 += bf(vB.y); b2 += bf(vB.z); b3 += bf(vB.w);
    }
    a0 += b0; a1 += b1; a2 += b2; a3 += b3;
    a0 += __shfl_xor(a0, 8); a0 += __shfl_xor(a0, 16); a0 += __shfl_xor(a0, 32);
    a1 += __shfl_xor(a1, 8); a1 += __shfl_xor(a1, 16); a1 += __shfl_xor(a1, 32);
    a2 += __shfl_xor(a2, 8); a2 += __shfl_xor(a2, 16); a2 += __shfl_xor(a2, 32);
    a3 += __shfl_xor(a3, 8); a3 += __shfl_xor(a3, 16); a3 += __shfl_xor(a3, 32);
    if (r == 0) {
        float rd = 1.0f / fmaxf((float)cdeg, 1.0f);
        float4 zz = *(const float4*)&z[node * 32 + c * 4];
        *(float4*)&out[node * 32 + c * 4] = make_float4(
            a0 * rd + zz.x, a1 * rd + zz.y, a2 * rd + zz.z, a3 * rd + zz.w);
    }
}

// ------------- overflow apply (dual list, expected 0 iterations) ----------
__global__ __launch_bounds__(256) void ovf_apply_kernel(
    const float* __restrict__ feat, const int* __restrict__ cnt,
    const int* __restrict__ ovfA_cnt, const int* __restrict__ ovfA,
    const int* __restrict__ ovfB_cnt, const int* __restrict__ ovfB,
    float* __restrict__ m)
{
    int nA = *ovfA_cnt; if (nA > OVF_CAP) nA = OVF_CAP;
    int nB = *ovfB_cnt; if (nB > OVF_CAP) nB = OVF_CAP;
    int total = (nA + nB) * 64;
    for (int t = blockIdx.x * 256 + threadIdx.x; t < total; t += gridDim.x * 256) {
        int o = t >> 6, f = t & 63;
        const int* L = (o < nA) ? &ovfA[2 * o] : &ovfB[2 * (o - nA)];
        int src = L[0], dst = L[1];
        float rd = 1.0f / fmaxf((float)cnt[dst], 1.0f);
        atomicAdd(&m[dst * 64 + f], feat[src * 64 + f] * rd);
    }
}

__global__ __launch_bounds__(256) void ovf_apply32_kernel(
    const u16* __restrict__ y2b, const int* __restrict__ cnt,
    const int* __restrict__ ovfA_cnt, const int* __restrict__ ovfA,
    const int* __restrict__ ovfB_cnt, const int* __restrict__ ovfB,
    float* __restrict__ out)
{
    int nA = *ovfA_cnt; if (nA > OVF_CAP) nA = OVF_CAP;
    int nB = *ovfB_cnt; if (nB > OVF_CAP) nB = OVF_CAP;
    int total = (nA + nB) * 32;
    for (int t = blockIdx.x * 256 + threadIdx.x; t < total; t += gridDim.x * 256) {
        int o = t >> 5, f = t & 31;
        const int* L = (o < nA) ? &ovfA[2 * o] : &ovfB[2 * (o - nA)];
        int src = L[0], dst = L[1];
        float rd = 1.0f / fmaxf((float)cnt[dst], 1.0f);
        atomicAdd(&out[dst * 32 + f], bf(y2b[src * 32 + f]) * rd);
    }
}

// ------------- hi/lo truncate-split of 8 floats to bf16 frags -------------
__device__ inline void split8(float4 v0, float4 v1, s16x8& hi, s16x8& lo) {
    float vs[8] = {v0.x, v0.y, v0.z, v0.w, v1.x, v1.y, v1.z, v1.w};
    s16x8 h, l;
    #pragma unroll
    for (int j = 0; j < 8; j++) {
        unsigned b  = __float_as_uint(vs[j]);
        float    hf = __uint_as_float(b & 0xFFFF0000u);
        float    r  = vs[j] - hf;            // exact
        h[j] = (short)(b >> 16);
        l[j] = (short)(__float_as_uint(r) >> 16);
    }
    hi = h; lo = l;
}

// ------------- GEMM layer 1: h = relu([m|x] @ B1^T + b1), K=128 -----------
template <int MT>
__global__ __launch_bounds__(256) void gemm1_kernel(
    const float* __restrict__ Am, const float* __restrict__ Ax,
    const short* __restrict__ Bhi, const short* __restrict__ Blo,
    const float* __restrict__ bias, float* __restrict__ out)
{
    int wave = (blockIdx.x * 256 + threadIdx.x) >> 6;
    int lane = threadIdx.x & 63;
    int m0   = wave * (MT * 16);
    if (m0 >= N_NODES) return;
    int quad = lane >> 4, l16 = lane & 15;

    f32x4 acc[MT][4];
    #pragma unroll
    for (int mt = 0; mt < MT; mt++)
        #pragma unroll
        for (int nt = 0; nt < 4; nt++) acc[mt][nt] = (f32x4)0.0f;

    #pragma unroll
    for (int half = 0; half < 2; half++) {
        const float* src = half ? Ax : Am;
        #pragma unroll
        for (int sub = 0; sub < 2; sub++) {
            int kf = sub * 32 + quad * 8;
            int kc = half * 64 + sub * 32 + quad * 8;
            s16x8 ahi[MT], alo[MT];
            #pragma unroll
            for (int mt = 0; mt < MT; mt++) {
                int row = m0 + mt * 16 + l16;
                row = row < N_NODES ? row : N_NODES - 1;
                const float4* p = (const float4*)&src[row * 64 + kf];
                split8(p[0], p[1], ahi[mt], alo[mt]);
            }
            #pragma unroll
            for (int nt = 0; nt < 4; nt++) {
                int n = nt * 16 + l16;
                s16x8 bh = *(const s16x8*)&Bhi[n * 128 + kc];
                s16x8 bl = *(const s16x8*)&Blo[n * 128 + kc];
                #pragma unroll
                for (int mt = 0; mt < MT; mt++) {
                    acc[mt][nt] = __builtin_amdgcn_mfma_f32_16x16x32_bf16(ahi[mt], bh, acc[mt][nt], 0, 0, 0);
                    acc[mt][nt] = __builtin_amdgcn_mfma_f32_16x16x32_bf16(alo[mt], bh, acc[mt][nt], 0, 0, 0);
                    acc[mt][nt] = __builtin_amdgcn_mfma_f32_16x16x32_bf16(ahi[mt], bl, acc[mt][nt], 0, 0, 0);
                    acc[mt][nt] = __builtin_amdgcn_mfma_f32_16x16x32_bf16(alo[mt], bl, acc[mt][nt], 0, 0, 0);
                }
            }
        }
    }
    #pragma unroll
    for (int nt = 0; nt < 4; nt++) {
        float bv = bias[nt * 16 + l16];
        #pragma unroll
        for (int mt = 0; mt < MT; mt++)
            #pragma unroll
            for (int r = 0; r < 4; r++) {
                int row = m0 + mt * 16 + quad * 4 + r;
                if (row < N_NODES)
                    out[row * 64 + nt * 16 + l16] = fmaxf(acc[mt][nt][r] + bv, 0.0f);
            }
    }
}

// ------------- GEMM layer 2: y2b = bf16(h@W2l^T) ; z = h@W2r^T + b2 -------
template <int MT>
__global__ __launch_bounds__(256) void gemm2_kernel(
    const float* __restrict__ h,
    const short* __restrict__ Bhi, const short* __restrict__ Blo,  // [64,64]
    const float* __restrict__ b2,
    u16* __restrict__ y2b, float* __restrict__ z)                  // [N,32] each
{
    int wave = (blockIdx.x * 256 + threadIdx.x) >> 6;
    int lane = threadIdx.x & 63;
    int m0   = wave * (MT * 16);
    if (m0 >= N_NODES) return;
    int quad = lane >> 4, l16 = lane & 15;

    f32x4 acc[MT][4];
    #pragma unroll
    for (int mt = 0; mt < MT; mt++)
        #pragma unroll
        for (int nt = 0; nt < 4; nt++) acc[mt][nt] = (f32x4)0.0f;

    #pragma unroll
    for (int sub = 0; sub < 2; sub++) {
        int kf = sub * 32 + quad * 8;
        s16x8 ahi[MT], alo[MT];
        #pragma unroll
        for (int mt = 0; mt < MT; mt++) {
            int row = m0 + mt * 16 + l16;
            row = row < N_NODES ? row : N_NODES - 1;
            const float4* p = (const float4*)&h[row * 64 + kf];
            split8(p[0], p[1], ahi[mt], alo[mt]);
        }
        #pragma unroll
        for (int nt = 0; nt < 4; nt++) {
            int n = nt * 16 + l16;
            s16x8 bh = *(const s16x8*)&Bhi[n * 64 + kf];
            s16x8 bl = *(const s16x8*)&Blo[n * 64 + kf];
            #pragma unroll
            for (int mt = 0; mt < MT; mt++) {
                acc[mt][nt] = __builtin_amdgcn_mfma_f32_16x16x32_bf16(ahi[mt], bh, acc[mt][nt], 0, 0, 0);
                acc[mt][nt] = __builtin_amdgcn_mfma_f32_16x16x32_bf16(alo[mt], bh, acc[mt][nt], 0, 0, 0);
                acc[mt][nt] = __builtin_amdgcn_mfma_f32_16x16x32_bf16(ahi[mt], bl, acc[mt][nt], 0, 0, 0);
                acc[mt][nt] = __builtin_amdgcn_mfma_f32_16x16x32_bf16(alo[mt], bl, acc[mt][nt], 0, 0, 0);
            }
        }
    }
    #pragma unroll
    for (int nt = 0; nt < 4; nt++) {
        bool  isz = nt >= 2;
        int   col = (isz ? nt - 2 : nt) * 16 + l16;
        float bv  = isz ? b2[col] : 0.0f;
        #pragma unroll
        for (int mt = 0; mt < MT; mt++)
            #pragma unroll
            for (int r = 0; r < 4; r++) {
                int row = m0 + mt * 16 + quad * 4 + r;
                if (row < N_NODES) {
                    float v = acc[mt][nt][r] + bv;
                    if (isz) z[row * 32 + col] = v;
                    else     y2b[row * 32 + col] = f2bf(v);
                }
            }
    }
}

extern "C" void kernel_launch(void* const* d_in, const int* in_sizes, int n_in,
                              void* d_out, int out_size, void* d_ws, size_t ws_size,
                              hipStream_t stream) {
    const float* x   = (const float*)d_in[0];
    const int*   ei1 = (const int*)d_in[1];
    const int*   ei2 = (const int*)d_in[3];
    const float* W1l = (const float*)d_in[5];
    const float* b1  = (const float*)d_in[6];
    const float* W1r = (const float*)d_in[7];
    const float* W2l = (const float*)d_in[8];
    const float* b2  = (const float*)d_in[9];
    const float* W2r = (const float*)d_in[10];
    float* out = (float*)d_out;

    // workspace layout. Aliases: barr -> m region (dead before gather writes
    // m); z/y2b -> m region (dead after gemm1); xb -> h region (dead before
    // gemm1 writes h).
    const size_t off_cnt   = 0;                                    // int[N]
    const size_t off_misc  = 400128;
    const size_t off_ovfAc = off_misc + 0;
    const size_t off_ovfBc = off_misc + 4;
    const size_t off_bcur  = off_misc + 256;                       // int[NB]
    const size_t off_ovfA  = off_misc + 1280;                      // 32 KB
    const size_t off_ovfB  = off_misc + 1280 + 8 * OVF_CAP;        // 32 KB
    const size_t off_slots = 467200;                               // int[N*CAP]
    const size_t off_m     = off_slots + (size_t)N_NODES * CAP * 4;
    const size_t off_h     = off_m + (size_t)N_NODES * 64 * 4;
    const size_t off_B1hi  = off_h + (size_t)N_NODES * 64 * 4;
    const size_t off_B1lo  = off_B1hi + 64 * 128 * 2;
    const size_t off_B2hi  = off_B1lo + 64 * 128 * 2;
    const size_t off_B2lo  = off_B2hi + 64 * 64 * 2;

    char*  ws     = (char*)d_ws;
    int*   cnt    = (int*)(ws + off_cnt);
    int*   ovfA_c = (int*)(ws + off_ovfAc);
    int*   ovfB_c = (int*)(ws + off_ovfBc);
    int*   bcur   = (int*)(ws + off_bcur);
    int*   ovfA   = (int*)(ws + off_ovfA);
    int*   ovfB   = (int*)(ws + off_ovfB);
    int*   slots  = (int*)(ws + off_slots);
    uint2* barr   = (uint2*)(ws + off_m);                          // alias m
    float* m      = (float*)(ws + off_m);
    float* h      = (float*)(ws + off_h);
    u16*   xb     = (u16*)(ws + off_h);                            // alias h
    float* z      = (float*)(ws + off_m);                          // alias m
    u16*   y2b    = (u16*)(ws + off_m + (size_t)N_NODES * 32 * 4); // alias m
    short* B1hi   = (short*)(ws + off_B1hi);
    short* B1lo   = (short*)(ws + off_B1lo);
    short* B2hi   = (short*)(ws + off_B2hi);
    short* B2lo   = (short*)(ws + off_B2lo);

    // zero counters + bucket cursors (+ovf lists) only (~67 KB)
    hipMemsetAsync(ws + off_misc, 0, off_slots - off_misc, stream);

    // prep: x->bf16 (6250 blocks) + weight hi/lo split (48 blocks)
    prep_kernel<<<6250 + 48, 256, 0, stream>>>(
        x, xb, W1l, W1r, W2l, W2r, B1hi, B1lo, B2hi, B2lo);

    // bucket build (shared by both layers)
    binA_kernel<<<(E_TOT + EPB_A - 1) / EPB_A, 256, 0, stream>>>(
        ei1, ei2, barr, bcur, ovfA_c, ovfA);
    binB_kernel<<<NB, 256, 0, stream>>>(barr, bcur, cnt, slots, ovfB_c, ovfB);
    ovf_fix_kernel<<<OVF_CAP / 256, 256, 0, stream>>>(ovfA_c, ovfA, cnt);

    // layer 1: gather-mean(bf16 x) -> m ; h = relu([m|x]@B1^T + b1)
    gather_mean_kernel<<<N_NODES / 4, 256, 0, stream>>>(xb, cnt, slots, m);
    ovf_apply_kernel<<<16, 256, 0, stream>>>(
        x, cnt, ovfA_c, ovfA, ovfB_c, ovfB, m);
    {
        int waves = (N_NODES + 31) / 32;   // MT=2
        gemm1_kernel<2><<<(waves + 3) / 4, 256, 0, stream>>>(
            m, x, B1hi, B1lo, b1, h);
    }

    // layer 2 (transform-first): y2b = bf16(h@W2l^T), z = h@W2r^T + b2;
    // out = gather-mean(y2b) + z
    {
        int waves = (N_NODES + 63) / 64;   // MT=4
        gemm2_kernel<4><<<(waves + 3) / 4, 256, 0, stream>>>(
            h, B2hi, B2lo, b2, y2b, z);
    }
    gather_mean32_kernel<<<N_NODES / 4, 256, 0, stream>>>(y2b, z, cnt, slots, out);
    ovf_apply32_kernel<<<16, 256, 0, stream>>>(
        y2b, cnt, ovfA_c, ovfA, ovfB_c, ovfB, out);
}

// Round 11
// 255.903 us; speedup vs baseline: 1.5121x; 1.0863x over previous
//
#include <hip/hip_runtime.h>

// GraphSAGE 2-layer, mean aggregation, fp32.
// R10 evidence: binA 44 us with VALUBusy 3%, Occupancy 7% — parallelism-
// starved (196 blocks < 256 CUs, serial 8192-edge chew). R11: EPB_A 2048
// (782 blocks), binB at 1024 threads (4x fewer serial iters), gathers
// deepened to 4 loads/lane in flight (R10 confirmed latency-bound).
// Structure otherwise identical to R10 (proven: 278 us, absmax 7.8e-3).

constexpr int N_NODES = 100000;
constexpr int E_HALF  = 800000;
constexpr int E_TOT   = 2 * E_HALF;
constexpr int CAP     = 64;      // slots per node
constexpr int OVF_CAP = 4096;    // overflow capacity (expected use: 0)
constexpr int NB      = 200;     // coarse buckets
constexpr int NPB     = 500;     // nodes per bucket
constexpr int BCAP    = 12288;   // edges per bucket (mean 8000, +48 sigma)
constexpr int EPB_A   = 2048;    // edges per pass-A block -> 782 blocks

typedef short  s16x8 __attribute__((ext_vector_type(8)));
typedef float  f32x4 __attribute__((ext_vector_type(4)));
typedef unsigned short u16;

__device__ inline float bf(u16 u) { return __uint_as_float(((unsigned)u) << 16); }
__device__ inline u16 f2bf(float v) {          // round-to-nearest-even bf16
    unsigned b = __float_as_uint(v);
    b += 0x7FFFu + ((b >> 16) & 1u);
    return (u16)(b >> 16);
}

// ------------- pass A: bin edges into 200 coarse dst-buckets --------------
__global__ __launch_bounds__(256) void binA_kernel(
    const int* __restrict__ ei1, const int* __restrict__ ei2,
    uint2* __restrict__ barr, int* __restrict__ bcur,
    int* __restrict__ ovfA_cnt, int* __restrict__ ovfA)
{
    __shared__ int hist[NB], base[NB], cur[NB];
    int tid = threadIdx.x;
    for (int t = tid; t < NB; t += 256) { hist[t] = 0; cur[t] = 0; }
    __syncthreads();
    int e0 = blockIdx.x * EPB_A;
    #pragma unroll
    for (int k = 0; k < EPB_A / 256; k++) {
        int e = e0 + k * 256 + tid;
        if (e >= E_TOT) break;
        const int* ei = (e < E_HALF) ? ei1 : ei2;
        int ee = (e < E_HALF) ? e : e - E_HALF;
        int dst = ei[E_HALF + ee];
        atomicAdd(&hist[dst / NPB], 1);
    }
    __syncthreads();
    for (int t = tid; t < NB; t += 256)
        base[t] = atomicAdd(&bcur[t], hist[t]);   // 200 fabric atomics/block
    __syncthreads();
    #pragma unroll
    for (int k = 0; k < EPB_A / 256; k++) {
        int e = e0 + k * 256 + tid;
        if (e >= E_TOT) break;
        const int* ei = (e < E_HALF) ? ei1 : ei2;
        int ee = (e < E_HALF) ? e : e - E_HALF;
        int dst = ei[E_HALF + ee];
        int src = ei[ee];
        int b   = dst / NPB;
        int pos = base[b] + atomicAdd(&cur[b], 1);
        if (pos < BCAP) {
            barr[b * BCAP + pos] = make_uint2((unsigned)src, (unsigned)dst);
        } else {
            int o = atomicAdd(ovfA_cnt, 1);
            if (o < OVF_CAP) { ovfA[2 * o] = src; ovfA[2 * o + 1] = dst; }
        }
    }
}

// ------------- pass B: per-bucket slot build with LDS counters ------------
__global__ __launch_bounds__(1024) void binB_kernel(
    const uint2* __restrict__ barr, const int* __restrict__ bcur,
    int* __restrict__ cnt, int* __restrict__ slots,
    int* __restrict__ ovfB_cnt, int* __restrict__ ovfB)
{
    __shared__ int lcnt[NPB];
    int tid = threadIdx.x, b = blockIdx.x;
    for (int t = tid; t < NPB; t += 1024) lcnt[t] = 0;
    __syncthreads();
    int nE = bcur[b]; if (nE > BCAP) nE = BCAP;
    int dbase = b * NPB;
    for (int i = tid; i < nE; i += 1024) {
        uint2 e = barr[b * BCAP + i];
        int dst = (int)e.y;
        int pos = atomicAdd(&lcnt[dst - dbase], 1);   // LDS atomic
        if (pos < CAP) {
            slots[dst * CAP + pos] = (int)e.x;        // L2-resident window
        } else {
            int o = atomicAdd(ovfB_cnt, 1);
            if (o < OVF_CAP) { ovfB[2 * o] = (int)e.x; ovfB[2 * o + 1] = dst; }
        }
    }
    __syncthreads();
    for (int t = tid; t < NPB; t += 1024) {
        int n = dbase + t;
        if (n < N_NODES) cnt[n] = lcnt[t];
    }
}

// ------------- cnt fix for pass-A overflow edges (expected 0) -------------
__global__ __launch_bounds__(256) void ovf_fix_kernel(
    const int* __restrict__ ovfA_cnt, const int* __restrict__ ovfA,
    int* __restrict__ cnt)
{
    int n = *ovfA_cnt; if (n > OVF_CAP) n = OVF_CAP;
    int t = blockIdx.x * 256 + threadIdx.x;
    if (t < n) atomicAdd(&cnt[ovfA[2 * t + 1]], 1);
}

// ------------- prep: x -> bf16 (blocks 0..6249) + weight split (48) -------
__global__ __launch_bounds__(256) void prep_kernel(
    const float* __restrict__ x, u16* __restrict__ xb,
    const float* __restrict__ W1l, const float* __restrict__ W1r,
    const float* __restrict__ W2l, const float* __restrict__ W2r,
    short* __restrict__ B1hi, short* __restrict__ B1lo,
    short* __restrict__ B2hi, short* __restrict__ B2lo)
{
    int blk = blockIdx.x;
    if (blk < 6250) {                        // N*16 float4 = 6250*256 exact
        int i = blk * 256 + threadIdx.x;
        float4 v = ((const float4*)x)[i];
        ushort4 rr;
        rr.x = f2bf(v.x); rr.y = f2bf(v.y); rr.z = f2bf(v.z); rr.w = f2bf(v.w);
        ((ushort4*)xb)[i] = rr;
        return;
    }
    int i = (blk - 6250) * 256 + threadIdx.x;   // 48*256 = 12288 exact
    float v; short* ph; short* pl; int idx;
    if (i < 64 * 128) {
        int o = i >> 7, k = i & 127;
        v = (k < 64) ? W1l[o * 64 + k] : W1r[o * 64 + (k - 64)];
        ph = B1hi; pl = B1lo; idx = i;
    } else {
        int j = i - 64 * 128;                   // j < 64*64
        int o = j >> 6, k = j & 63;
        v = (o < 32) ? W2l[o * 64 + k] : W2r[(o - 32) * 64 + k];
        ph = B2hi; pl = B2lo; idx = j;
    }
    unsigned b  = __float_as_uint(v);
    float    hf = __uint_as_float(b & 0xFFFF0000u);
    float    r  = v - hf;
    ph[idx] = (short)(b >> 16);
    pl[idx] = (short)(__float_as_uint(r) >> 16);
}

// ------------- gather-mean 64-wide: wave/node, 4 loads/lane in flight -----
__global__ __launch_bounds__(256) void gather_mean_kernel(
    const u16*  __restrict__ xb,      // [N,64] bf16
    const int*  __restrict__ cnt,     // [N]
    const int*  __restrict__ slots,   // [N,CAP]
    float*      __restrict__ m)       // [N,64] mean (fp32)
{
    int node = blockIdx.x * 4 + (threadIdx.x >> 6);
    int lane = threadIdx.x & 63;
    int r    = lane >> 4;             // row subgroup 0..3
    int c    = lane & 15;             // feature block (4 feats)
    if (node >= N_NODES) return;
    int cdeg = cnt[node];
    int cc   = cdeg < CAP ? cdeg : CAP;
    int slotv = (lane < cc) ? slots[node * CAP + lane] : 0;
    float a0 = 0.f, a1 = 0.f, a2 = 0.f, a3 = 0.f;
    float b0 = 0.f, b1 = 0.f, b2 = 0.f, b3 = 0.f;
    float c0 = 0.f, c1 = 0.f, c2 = 0.f, c3 = 0.f;
    float d0 = 0.f, d1 = 0.f, d2 = 0.f, d3 = 0.f;
    for (int i = 0; i < cc; i += 16) {
        int iA = i + r, iB = i + 4 + r, iC = i + 8 + r, iD = i + 12 + r;
        int sA = __shfl(slotv, iA & 63);
        int sB = __shfl(slotv, iB & 63);
        int sC = __shfl(slotv, iC & 63);
        int sD = __shfl(slotv, iD & 63);
        ushort4 vA = make_ushort4(0,0,0,0), vB = make_ushort4(0,0,0,0);
        ushort4 vC = make_ushort4(0,0,0,0), vD = make_ushort4(0,0,0,0);
        if (iA < cc) vA = *(const ushort4*)&xb[sA * 64 + c * 4];
        if (iB < cc) vB = *(const ushort4*)&xb[sB * 64 + c * 4];
        if (iC < cc) vC = *(const ushort4*)&xb[sC * 64 + c * 4];
        if (iD < cc) vD = *(const ushort4*)&xb[sD * 64 + c * 4];
        a0 += bf(vA.x); a1 += bf(vA.y); a2 += bf(vA.z); a3 += bf(vA.w);
        b0 += bf(vB.x); b1 += bf(vB.y); b2 += bf(vB.z); b3 += bf(vB.w);
        c0 += bf(vC.x); c1 += bf(vC.y); c2 += bf(vC.z); c3 += bf(vC.w);
        d0 += bf(vD.x); d1 += bf(vD.y); d2 += bf(vD.z); d3 += bf(vD.w);
    }
    a0 += b0 + c0 + d0; a1 += b1 + c1 + d1;
    a2 += b2 + c2 + d2; a3 += b3 + c3 + d3;
    a0 += __shfl_xor(a0, 16); a0 += __shfl_xor(a0, 32);
    a1 += __shfl_xor(a1, 16); a1 += __shfl_xor(a1, 32);
    a2 += __shfl_xor(a2, 16); a2 += __shfl_xor(a2, 32);
    a3 += __shfl_xor(a3, 16); a3 += __shfl_xor(a3, 32);
    if (r == 0) {
        float rd = 1.0f / fmaxf((float)cdeg, 1.0f);
        *(float4*)&m[node * 64 + c * 4] =
            make_float4(a0 * rd, a1 * rd, a2 * rd, a3 * rd);
    }
}

// ------------- gather-mean 32-wide + add z -> out, 4 loads/lane -----------
__global__ __launch_bounds__(256) void gather_mean32_kernel(
    const u16*  __restrict__ y2b,     // [N,32] bf16
    const float* __restrict__ z,      // [N,32] self term (bias included)
    const int*  __restrict__ cnt,
    const int*  __restrict__ slots,
    float*      __restrict__ out)     // [N,32]
{
    int node = blockIdx.x * 4 + (threadIdx.x >> 6);
    int lane = threadIdx.x & 63;
    int r    = lane >> 3;             // row subgroup 0..7
    int c    = lane & 7;              // feature block (4 feats)
    if (node >= N_NODES) return;
    int cdeg = cnt[node];
    int cc   = cdeg < CAP ? cdeg : CAP;
    int slotv = (lane < cc) ? slots[node * CAP + lane] : 0;
    float a0 = 0.f, a1 = 0.f, a2 = 0.f, a3 = 0.f;
    float b0 = 0.f, b1 = 0.f, b2 = 0.f, b3 = 0.f;
    float c0 = 0.f, c1 = 0.f, c2 = 0.f, c3 = 0.f;
    float d0 = 0.f, d1 = 0.f, d2 = 0.f, d3 = 0.f;
    for (int i = 0; i < cc; i += 32) {
        int iA = i + r, iB = i + 8 + r, iC = i + 16 + r, iD = i + 24 + r;
        int sA = __shfl(slotv, iA & 63);
        int sB = __shfl(slotv, iB & 63);
        int sC = __shfl(slotv, iC & 63);
        int sD = __shfl(slotv, iD & 63);
        ushort4 vA = make_ushort4(0,0,0,0), vB = make_ushort4(0,0,0,0);
        ushort4 vC = make_ushort4(0,0,0,0), vD = make_ushort4(0,0,0,0);
        if (iA < cc) vA = *(const ushort4*)&y2b[sA * 32 + c * 4];
        if (iB < cc) vB = *(const ushort4*)&y2b[sB * 32 + c * 4];
        if (iC < cc) vC = *(const ushort4*)&y2b[sC * 32 + c * 4];
        if (iD < cc) vD = *(const ushort4*)&y2b[sD * 32 + c * 4];
        a0 += bf(vA.x); a1 += bf(vA.y); a2 += bf(vA.z); a3 += bf(vA.w);
        b0 += bf(vB.x); b1 += bf(vB.y); b2 += bf(vB.z); b3 += bf(vB.w);
        c0 += bf(vC.x); c1 += bf(vC.y); c2 += bf(vC.z); c3 += bf(vC.w);
        d0 += bf(vD.x); d1 += bf(vD.y); d2 += bf(vD.z); d3 += bf(vD.w);
    }
    a0 += b0 + c0 + d0; a1 += b1 + c1 + d1;
    a2 += b2 + c2 + d2; a3 += b3 + c3 + d3;
    a0 += __shfl_xor(a0, 8); a0 += __shfl_xor(a0, 16); a0 += __shfl_xor(a0, 32);
    a1 += __shfl_xor(a1, 8); a1 += __shfl_xor(a1, 16); a1 += __shfl_xor(a1, 32);
    a2 += __shfl_xor(a2, 8); a2 += __shfl_xor(a2, 16); a2 += __shfl_xor(a2, 32);
    a3 += __shfl_xor(a3, 8); a3 += __shfl_xor(a3, 16); a3 += __shfl_xor(a3, 32);
    if (r == 0) {
        float rd = 1.0f / fmaxf((float)cdeg, 1.0f);
        float4 zz = *(const float4*)&z[node * 32 + c * 4];
        *(float4*)&out[node * 32 + c * 4] = make_float4(
            a0 * rd + zz.x, a1 * rd + zz.y, a2 * rd + zz.z, a3 * rd + zz.w);
    }
}

// ------------- overflow apply (dual list, expected 0 iterations) ----------
__global__ __launch_bounds__(256) void ovf_apply_kernel(
    const float* __restrict__ feat, const int* __restrict__ cnt,
    const int* __restrict__ ovfA_cnt, const int* __restrict__ ovfA,
    const int* __restrict__ ovfB_cnt, const int* __restrict__ ovfB,
    float* __restrict__ m)
{
    int nA = *ovfA_cnt; if (nA > OVF_CAP) nA = OVF_CAP;
    int nB = *ovfB_cnt; if (nB > OVF_CAP) nB = OVF_CAP;
    int total = (nA + nB) * 64;
    for (int t = blockIdx.x * 256 + threadIdx.x; t < total; t += gridDim.x * 256) {
        int o = t >> 6, f = t & 63;
        const int* L = (o < nA) ? &ovfA[2 * o] : &ovfB[2 * (o - nA)];
        int src = L[0], dst = L[1];
        float rd = 1.0f / fmaxf((float)cnt[dst], 1.0f);
        atomicAdd(&m[dst * 64 + f], feat[src * 64 + f] * rd);
    }
}

__global__ __launch_bounds__(256) void ovf_apply32_kernel(
    const u16* __restrict__ y2b, const int* __restrict__ cnt,
    const int* __restrict__ ovfA_cnt, const int* __restrict__ ovfA,
    const int* __restrict__ ovfB_cnt, const int* __restrict__ ovfB,
    float* __restrict__ out)
{
    int nA = *ovfA_cnt; if (nA > OVF_CAP) nA = OVF_CAP;
    int nB = *ovfB_cnt; if (nB > OVF_CAP) nB = OVF_CAP;
    int total = (nA + nB) * 32;
    for (int t = blockIdx.x * 256 + threadIdx.x; t < total; t += gridDim.x * 256) {
        int o = t >> 5, f = t & 31;
        const int* L = (o < nA) ? &ovfA[2 * o] : &ovfB[2 * (o - nA)];
        int src = L[0], dst = L[1];
        float rd = 1.0f / fmaxf((float)cnt[dst], 1.0f);
        atomicAdd(&out[dst * 32 + f], bf(y2b[src * 32 + f]) * rd);
    }
}

// ------------- hi/lo truncate-split of 8 floats to bf16 frags -------------
__device__ inline void split8(float4 v0, float4 v1, s16x8& hi, s16x8& lo) {
    float vs[8] = {v0.x, v0.y, v0.z, v0.w, v1.x, v1.y, v1.z, v1.w};
    s16x8 h, l;
    #pragma unroll
    for (int j = 0; j < 8; j++) {
        unsigned b  = __float_as_uint(vs[j]);
        float    hf = __uint_as_float(b & 0xFFFF0000u);
        float    r  = vs[j] - hf;            // exact
        h[j] = (short)(b >> 16);
        l[j] = (short)(__float_as_uint(r) >> 16);
    }
    hi = h; lo = l;
}

// ------------- GEMM layer 1: h = relu([m|x] @ B1^T + b1), K=128 -----------
template <int MT>
__global__ __launch_bounds__(256) void gemm1_kernel(
    const float* __restrict__ Am, const float* __restrict__ Ax,
    const short* __restrict__ Bhi, const short* __restrict__ Blo,
    const float* __restrict__ bias, float* __restrict__ out)
{
    int wave = (blockIdx.x * 256 + threadIdx.x) >> 6;
    int lane = threadIdx.x & 63;
    int m0   = wave * (MT * 16);
    if (m0 >= N_NODES) return;
    int quad = lane >> 4, l16 = lane & 15;

    f32x4 acc[MT][4];
    #pragma unroll
    for (int mt = 0; mt < MT; mt++)
        #pragma unroll
        for (int nt = 0; nt < 4; nt++) acc[mt][nt] = (f32x4)0.0f;

    #pragma unroll
    for (int half = 0; half < 2; half++) {
        const float* src = half ? Ax : Am;
        #pragma unroll
        for (int sub = 0; sub < 2; sub++) {
            int kf = sub * 32 + quad * 8;
            int kc = half * 64 + sub * 32 + quad * 8;
            s16x8 ahi[MT], alo[MT];
            #pragma unroll
            for (int mt = 0; mt < MT; mt++) {
                int row = m0 + mt * 16 + l16;
                row = row < N_NODES ? row : N_NODES - 1;
                const float4* p = (const float4*)&src[row * 64 + kf];
                split8(p[0], p[1], ahi[mt], alo[mt]);
            }
            #pragma unroll
            for (int nt = 0; nt < 4; nt++) {
                int n = nt * 16 + l16;
                s16x8 bh = *(const s16x8*)&Bhi[n * 128 + kc];
                s16x8 bl = *(const s16x8*)&Blo[n * 128 + kc];
                #pragma unroll
                for (int mt = 0; mt < MT; mt++) {
                    acc[mt][nt] = __builtin_amdgcn_mfma_f32_16x16x32_bf16(ahi[mt], bh, acc[mt][nt], 0, 0, 0);
                    acc[mt][nt] = __builtin_amdgcn_mfma_f32_16x16x32_bf16(alo[mt], bh, acc[mt][nt], 0, 0, 0);
                    acc[mt][nt] = __builtin_amdgcn_mfma_f32_16x16x32_bf16(ahi[mt], bl, acc[mt][nt], 0, 0, 0);
                    acc[mt][nt] = __builtin_amdgcn_mfma_f32_16x16x32_bf16(alo[mt], bl, acc[mt][nt], 0, 0, 0);
                }
            }
        }
    }
    #pragma unroll
    for (int nt = 0; nt < 4; nt++) {
        float bv = bias[nt * 16 + l16];
        #pragma unroll
        for (int mt = 0; mt < MT; mt++)
            #pragma unroll
            for (int r = 0; r < 4; r++) {
                int row = m0 + mt * 16 + quad * 4 + r;
                if (row < N_NODES)
                    out[row * 64 + nt * 16 + l16] = fmaxf(acc[mt][nt][r] + bv, 0.0f);
            }
    }
}

// ------------- GEMM layer 2: y2b = bf16(h@W2l^T) ; z = h@W2r^T + b2 -------
template <int MT>
__global__ __launch_bounds__(256) void gemm2_kernel(
    const float* __restrict__ h,
    const short* __restrict__ Bhi, const short* __restrict__ Blo,  // [64,64]
    const float* __restrict__ b2,
    u16* __restrict__ y2b, float* __restrict__ z)                  // [N,32] each
{
    int wave = (blockIdx.x * 256 + threadIdx.x) >> 6;
    int lane = threadIdx.x & 63;
    int m0   = wave * (MT * 16);
    if (m0 >= N_NODES) return;
    int quad = lane >> 4, l16 = lane & 15;

    f32x4 acc[MT][4];
    #pragma unroll
    for (int mt = 0; mt < MT; mt++)
        #pragma unroll
        for (int nt = 0; nt < 4; nt++) acc[mt][nt] = (f32x4)0.0f;

    #pragma unroll
    for (int sub = 0; sub < 2; sub++) {
        int kf = sub * 32 + quad * 8;
        s16x8 ahi[MT], alo[MT];
        #pragma unroll
        for (int mt = 0; mt < MT; mt++) {
            int row = m0 + mt * 16 + l16;
            row = row < N_NODES ? row : N_NODES - 1;
            const float4* p = (const float4*)&h[row * 64 + kf];
            split8(p[0], p[1], ahi[mt], alo[mt]);
        }
        #pragma unroll
        for (int nt = 0; nt < 4; nt++) {
            int n = nt * 16 + l16;
            s16x8 bh = *(const s16x8*)&Bhi[n * 64 + kf];
            s16x8 bl = *(const s16x8*)&Blo[n * 64 + kf];
            #pragma unroll
            for (int mt = 0; mt < MT; mt++) {
                acc[mt][nt] = __builtin_amdgcn_mfma_f32_16x16x32_bf16(ahi[mt], bh, acc[mt][nt], 0, 0, 0);
                acc[mt][nt] = __builtin_amdgcn_mfma_f32_16x16x32_bf16(alo[mt], bh, acc[mt][nt], 0, 0, 0);
                acc[mt][nt] = __builtin_amdgcn_mfma_f32_16x16x32_bf16(ahi[mt], bl, acc[mt][nt], 0, 0, 0);
                acc[mt][nt] = __builtin_amdgcn_mfma_f32_16x16x32_bf16(alo[mt], bl, acc[mt][nt], 0, 0, 0);
            }
        }
    }
    #pragma unroll
    for (int nt = 0; nt < 4; nt++) {
        bool  isz = nt >= 2;
        int   col = (isz ? nt - 2 : nt) * 16 + l16;
        float bv  = isz ? b2[col] : 0.0f;
        #pragma unroll
        for (int mt = 0; mt < MT; mt++)
            #pragma unroll
            for (int r = 0; r < 4; r++) {
                int row = m0 + mt * 16 + quad * 4 + r;
                if (row < N_NODES) {
                    float v = acc[mt][nt][r] + bv;
                    if (isz) z[row * 32 + col] = v;
                    else     y2b[row * 32 + col] = f2bf(v);
                }
            }
    }
}

extern "C" void kernel_launch(void* const* d_in, const int* in_sizes, int n_in,
                              void* d_out, int out_size, void* d_ws, size_t ws_size,
                              hipStream_t stream) {
    const float* x   = (const float*)d_in[0];
    const int*   ei1 = (const int*)d_in[1];
    const int*   ei2 = (const int*)d_in[3];
    const float* W1l = (const float*)d_in[5];
    const float* b1  = (const float*)d_in[6];
    const float* W1r = (const float*)d_in[7];
    const float* W2l = (const float*)d_in[8];
    const float* b2  = (const float*)d_in[9];
    const float* W2r = (const float*)d_in[10];
    float* out = (float*)d_out;

    // workspace layout. Aliases: barr -> m region (dead before gather writes
    // m); z/y2b -> m region (dead after gemm1); xb -> h region (dead before
    // gemm1 writes h).
    const size_t off_cnt   = 0;                                    // int[N]
    const size_t off_misc  = 400128;
    const size_t off_ovfAc = off_misc + 0;
    const size_t off_ovfBc = off_misc + 4;
    const size_t off_bcur  = off_misc + 256;                       // int[NB]
    const size_t off_ovfA  = off_misc + 1280;                      // 32 KB
    const size_t off_ovfB  = off_misc + 1280 + 8 * OVF_CAP;        // 32 KB
    const size_t off_slots = 467200;                               // int[N*CAP]
    const size_t off_m     = off_slots + (size_t)N_NODES * CAP * 4;
    const size_t off_h     = off_m + (size_t)N_NODES * 64 * 4;
    const size_t off_B1hi  = off_h + (size_t)N_NODES * 64 * 4;
    const size_t off_B1lo  = off_B1hi + 64 * 128 * 2;
    const size_t off_B2hi  = off_B1lo + 64 * 128 * 2;
    const size_t off_B2lo  = off_B2hi + 64 * 64 * 2;

    char*  ws     = (char*)d_ws;
    int*   cnt    = (int*)(ws + off_cnt);
    int*   ovfA_c = (int*)(ws + off_ovfAc);
    int*   ovfB_c = (int*)(ws + off_ovfBc);
    int*   bcur   = (int*)(ws + off_bcur);
    int*   ovfA   = (int*)(ws + off_ovfA);
    int*   ovfB   = (int*)(ws + off_ovfB);
    int*   slots  = (int*)(ws + off_slots);
    uint2* barr   = (uint2*)(ws + off_m);                          // alias m
    float* m      = (float*)(ws + off_m);
    float* h      = (float*)(ws + off_h);
    u16*   xb     = (u16*)(ws + off_h);                            // alias h
    float* z      = (float*)(ws + off_m);                          // alias m
    u16*   y2b    = (u16*)(ws + off_m + (size_t)N_NODES * 32 * 4); // alias m
    short* B1hi   = (short*)(ws + off_B1hi);
    short* B1lo   = (short*)(ws + off_B1lo);
    short* B2hi   = (short*)(ws + off_B2hi);
    short* B2lo   = (short*)(ws + off_B2lo);

    // zero counters + bucket cursors (+ovf lists) only (~67 KB)
    hipMemsetAsync(ws + off_misc, 0, off_slots - off_misc, stream);

    // prep: x->bf16 (6250 blocks) + weight hi/lo split (48 blocks)
    prep_kernel<<<6250 + 48, 256, 0, stream>>>(
        x, xb, W1l, W1r, W2l, W2r, B1hi, B1lo, B2hi, B2lo);

    // bucket build (shared by both layers)
    binA_kernel<<<(E_TOT + EPB_A - 1) / EPB_A, 256, 0, stream>>>(
        ei1, ei2, barr, bcur, ovfA_c, ovfA);
    binB_kernel<<<NB, 1024, 0, stream>>>(barr, bcur, cnt, slots, ovfB_c, ovfB);
    ovf_fix_kernel<<<OVF_CAP / 256, 256, 0, stream>>>(ovfA_c, ovfA, cnt);

    // layer 1: gather-mean(bf16 x) -> m ; h = relu([m|x]@B1^T + b1)
    gather_mean_kernel<<<N_NODES / 4, 256, 0, stream>>>(xb, cnt, slots, m);
    ovf_apply_kernel<<<16, 256, 0, stream>>>(
        x, cnt, ovfA_c, ovfA, ovfB_c, ovfB, m);
    {
        int waves = (N_NODES + 31) / 32;   // MT=2
        gemm1_kernel<2><<<(waves + 3) / 4, 256, 0, stream>>>(
            m, x, B1hi, B1lo, b1, h);
    }

    // layer 2 (transform-first): y2b = bf16(h@W2l^T), z = h@W2r^T + b2;
    // out = gather-mean(y2b) + z
    {
        int waves = (N_NODES + 63) / 64;   // MT=4
        gemm2_kernel<4><<<(waves + 3) / 4, 256, 0, stream>>>(
            h, B2hi, B2lo, b2, y2b, z);
    }
    gather_mean32_kernel<<<N_NODES / 4, 256, 0, stream>>>(y2b, z, cnt, slots, out);
    ovf_apply32_kernel<<<16, 256, 0, stream>>>(
        y2b, cnt, ovfA_c, ovfA, ovfB_c, ovfB, out);
}

// Round 12
// 254.955 us; speedup vs baseline: 1.5178x; 1.0037x over previous
//
#include <hip/hip_runtime.h>

// GraphSAGE 2-layer, mean aggregation, fp32.
// R11 evidence: binA stuck at 42 us (occupancy fix didn't help; WRITE_SIZE
// tripled) -> bound by phase-3 uncoalesced scatter stores (1.6M random 8B).
// R12: binA stages edges sorted-by-bucket in LDS (block scan of hist +
// insert-time global address), then writes dense runs -> coalesced.
// ~86 us of harness ws re-poison fills are in the timed window (fixed cost).
// Everything else identical to R11 (proven: 256 us, absmax 7.8e-3).

constexpr int N_NODES = 100000;
constexpr int E_HALF  = 800000;
constexpr int E_TOT   = 2 * E_HALF;
constexpr int CAP     = 64;      // slots per node
constexpr int OVF_CAP = 4096;    // overflow capacity (expected use: 0)
constexpr int NB      = 200;     // coarse buckets
constexpr int NPB     = 500;     // nodes per bucket
constexpr int BCAP    = 12288;   // edges per bucket (mean 8000, +48 sigma)
constexpr int EPB_A   = 2048;    // edges per pass-A block -> 782 blocks

typedef short  s16x8 __attribute__((ext_vector_type(8)));
typedef float  f32x4 __attribute__((ext_vector_type(4)));
typedef unsigned short u16;

__device__ inline float bf(u16 u) { return __uint_as_float(((unsigned)u) << 16); }
__device__ inline u16 f2bf(float v) {          // round-to-nearest-even bf16
    unsigned b = __float_as_uint(v);
    b += 0x7FFFu + ((b >> 16) & 1u);
    return (u16)(b >> 16);
}

// ------------- pass A: bin edges, LDS-staged coalesced write-out ----------
__global__ __launch_bounds__(256) void binA_kernel(
    const int* __restrict__ ei1, const int* __restrict__ ei2,
    uint2* __restrict__ barr, int* __restrict__ bcur,
    int* __restrict__ ovfA_cnt, int* __restrict__ ovfA)
{
    __shared__ int   hist[NB], base[NB], cur[NB], lofs[NB];
    __shared__ int   scan[256];
    __shared__ int   aux[EPB_A];
    __shared__ uint2 staged[EPB_A];
    int tid = threadIdx.x;
    for (int t = tid; t < NB; t += 256) { hist[t] = 0; cur[t] = 0; }
    __syncthreads();

    // phase 1: histogram
    int e0 = blockIdx.x * EPB_A;
    #pragma unroll
    for (int k = 0; k < EPB_A / 256; k++) {
        int e = e0 + k * 256 + tid;
        if (e >= E_TOT) break;
        const int* ei = (e < E_HALF) ? ei1 : ei2;
        int ee = (e < E_HALF) ? e : e - E_HALF;
        int dst = ei[E_HALF + ee];
        atomicAdd(&hist[dst / NPB], 1);
    }
    __syncthreads();

    // phase 2a: block-exclusive scan of hist (Hillis-Steele over 256)
    int v = (tid < NB) ? hist[tid] : 0;
    scan[tid] = v;
    __syncthreads();
    #pragma unroll
    for (int off = 1; off < 256; off <<= 1) {
        int u = (tid >= off) ? scan[tid - off] : 0;
        __syncthreads();
        scan[tid] += u;
        __syncthreads();
    }
    if (tid < NB) lofs[tid] = scan[tid] - v;
    // phase 2b: reserve global windows (200 fabric atomics/block)
    if (tid < NB) base[tid] = atomicAdd(&bcur[tid], hist[tid]);
    __syncthreads();

    // phase 3: stage edges into LDS, bucket-sorted; record global addr
    #pragma unroll
    for (int k = 0; k < EPB_A / 256; k++) {
        int e = e0 + k * 256 + tid;
        if (e >= E_TOT) break;
        const int* ei = (e < E_HALF) ? ei1 : ei2;
        int ee = (e < E_HALF) ? e : e - E_HALF;
        int dst = ei[E_HALF + ee];
        int src = ei[ee];
        int b   = dst / NPB;
        int rank = atomicAdd(&cur[b], 1);          // LDS atomic
        int p    = lofs[b] + rank;
        int gpos = base[b] + rank;
        if (gpos < BCAP) {
            staged[p] = make_uint2((unsigned)src, (unsigned)dst);
            aux[p]    = b * BCAP + gpos;
        } else {
            aux[p] = -1;
            int o = atomicAdd(ovfA_cnt, 1);
            if (o < OVF_CAP) { ovfA[2 * o] = src; ovfA[2 * o + 1] = dst; }
        }
    }
    __syncthreads();

    // phase 4: dense write-out (runs are contiguous -> coalesced)
    int tot = scan[255];
    for (int i = tid; i < tot; i += 256) {
        int a = aux[i];
        if (a >= 0) barr[a] = staged[i];
    }
}

// ------------- pass B: per-bucket slot build with LDS counters ------------
__global__ __launch_bounds__(1024) void binB_kernel(
    const uint2* __restrict__ barr, const int* __restrict__ bcur,
    int* __restrict__ cnt, int* __restrict__ slots,
    int* __restrict__ ovfB_cnt, int* __restrict__ ovfB)
{
    __shared__ int lcnt[NPB];
    int tid = threadIdx.x, b = blockIdx.x;
    for (int t = tid; t < NPB; t += 1024) lcnt[t] = 0;
    __syncthreads();
    int nE = bcur[b]; if (nE > BCAP) nE = BCAP;
    int dbase = b * NPB;
    for (int i = tid; i < nE; i += 1024) {
        uint2 e = barr[b * BCAP + i];
        int dst = (int)e.y;
        int pos = atomicAdd(&lcnt[dst - dbase], 1);   // LDS atomic
        if (pos < CAP) {
            slots[dst * CAP + pos] = (int)e.x;        // L2-resident window
        } else {
            int o = atomicAdd(ovfB_cnt, 1);
            if (o < OVF_CAP) { ovfB[2 * o] = (int)e.x; ovfB[2 * o + 1] = dst; }
        }
    }
    __syncthreads();
    for (int t = tid; t < NPB; t += 1024) {
        int n = dbase + t;
        if (n < N_NODES) cnt[n] = lcnt[t];
    }
}

// ------------- cnt fix for pass-A overflow edges (expected 0) -------------
__global__ __launch_bounds__(256) void ovf_fix_kernel(
    const int* __restrict__ ovfA_cnt, const int* __restrict__ ovfA,
    int* __restrict__ cnt)
{
    int n = *ovfA_cnt; if (n > OVF_CAP) n = OVF_CAP;
    int t = blockIdx.x * 256 + threadIdx.x;
    if (t < n) atomicAdd(&cnt[ovfA[2 * t + 1]], 1);
}

// ------------- prep: x -> bf16 (blocks 0..6249) + weight split (48) -------
__global__ __launch_bounds__(256) void prep_kernel(
    const float* __restrict__ x, u16* __restrict__ xb,
    const float* __restrict__ W1l, const float* __restrict__ W1r,
    const float* __restrict__ W2l, const float* __restrict__ W2r,
    short* __restrict__ B1hi, short* __restrict__ B1lo,
    short* __restrict__ B2hi, short* __restrict__ B2lo)
{
    int blk = blockIdx.x;
    if (blk < 6250) {                        // N*16 float4 = 6250*256 exact
        int i = blk * 256 + threadIdx.x;
        float4 v = ((const float4*)x)[i];
        ushort4 rr;
        rr.x = f2bf(v.x); rr.y = f2bf(v.y); rr.z = f2bf(v.z); rr.w = f2bf(v.w);
        ((ushort4*)xb)[i] = rr;
        return;
    }
    int i = (blk - 6250) * 256 + threadIdx.x;   // 48*256 = 12288 exact
    float v; short* ph; short* pl; int idx;
    if (i < 64 * 128) {
        int o = i >> 7, k = i & 127;
        v = (k < 64) ? W1l[o * 64 + k] : W1r[o * 64 + (k - 64)];
        ph = B1hi; pl = B1lo; idx = i;
    } else {
        int j = i - 64 * 128;                   // j < 64*64
        int o = j >> 6, k = j & 63;
        v = (o < 32) ? W2l[o * 64 + k] : W2r[(o - 32) * 64 + k];
        ph = B2hi; pl = B2lo; idx = j;
    }
    unsigned b  = __float_as_uint(v);
    float    hf = __uint_as_float(b & 0xFFFF0000u);
    float    r  = v - hf;
    ph[idx] = (short)(b >> 16);
    pl[idx] = (short)(__float_as_uint(r) >> 16);
}

// ------------- gather-mean 64-wide: wave/node, 4 loads/lane in flight -----
__global__ __launch_bounds__(256) void gather_mean_kernel(
    const u16*  __restrict__ xb,      // [N,64] bf16
    const int*  __restrict__ cnt,     // [N]
    const int*  __restrict__ slots,   // [N,CAP]
    float*      __restrict__ m)       // [N,64] mean (fp32)
{
    int node = blockIdx.x * 4 + (threadIdx.x >> 6);
    int lane = threadIdx.x & 63;
    int r    = lane >> 4;             // row subgroup 0..3
    int c    = lane & 15;             // feature block (4 feats)
    if (node >= N_NODES) return;
    int cdeg = cnt[node];
    int cc   = cdeg < CAP ? cdeg : CAP;
    int slotv = (lane < cc) ? slots[node * CAP + lane] : 0;
    float a0 = 0.f, a1 = 0.f, a2 = 0.f, a3 = 0.f;
    float b0 = 0.f, b1 = 0.f, b2 = 0.f, b3 = 0.f;
    float c0 = 0.f, c1 = 0.f, c2 = 0.f, c3 = 0.f;
    float d0 = 0.f, d1 = 0.f, d2 = 0.f, d3 = 0.f;
    for (int i = 0; i < cc; i += 16) {
        int iA = i + r, iB = i + 4 + r, iC = i + 8 + r, iD = i + 12 + r;
        int sA = __shfl(slotv, iA & 63);
        int sB = __shfl(slotv, iB & 63);
        int sC = __shfl(slotv, iC & 63);
        int sD = __shfl(slotv, iD & 63);
        ushort4 vA = make_ushort4(0,0,0,0), vB = make_ushort4(0,0,0,0);
        ushort4 vC = make_ushort4(0,0,0,0), vD = make_ushort4(0,0,0,0);
        if (iA < cc) vA = *(const ushort4*)&xb[sA * 64 + c * 4];
        if (iB < cc) vB = *(const ushort4*)&xb[sB * 64 + c * 4];
        if (iC < cc) vC = *(const ushort4*)&xb[sC * 64 + c * 4];
        if (iD < cc) vD = *(const ushort4*)&xb[sD * 64 + c * 4];
        a0 += bf(vA.x); a1 += bf(vA.y); a2 += bf(vA.z); a3 += bf(vA.w);
        b0 += bf(vB.x); b1 += bf(vB.y); b2 += bf(vB.z); b3 += bf(vB.w);
        c0 += bf(vC.x); c1 += bf(vC.y); c2 += bf(vC.z); c3 += bf(vC.w);
        d0 += bf(vD.x); d1 += bf(vD.y); d2 += bf(vD.z); d3 += bf(vD.w);
    }
    a0 += b0 + c0 + d0; a1 += b1 + c1 + d1;
    a2 += b2 + c2 + d2; a3 += b3 + c3 + d3;
    a0 += __shfl_xor(a0, 16); a0 += __shfl_xor(a0, 32);
    a1 += __shfl_xor(a1, 16); a1 += __shfl_xor(a1, 32);
    a2 += __shfl_xor(a2, 16); a2 += __shfl_xor(a2, 32);
    a3 += __shfl_xor(a3, 16); a3 += __shfl_xor(a3, 32);
    if (r == 0) {
        float rd = 1.0f / fmaxf((float)cdeg, 1.0f);
        *(float4*)&m[node * 64 + c * 4] =
            make_float4(a0 * rd, a1 * rd, a2 * rd, a3 * rd);
    }
}

// ------------- gather-mean 32-wide + add z -> out, 4 loads/lane -----------
__global__ __launch_bounds__(256) void gather_mean32_kernel(
    const u16*  __restrict__ y2b,     // [N,32] bf16
    const float* __restrict__ z,      // [N,32] self term (bias included)
    const int*  __restrict__ cnt,
    const int*  __restrict__ slots,
    float*      __restrict__ out)     // [N,32]
{
    int node = blockIdx.x * 4 + (threadIdx.x >> 6);
    int lane = threadIdx.x & 63;
    int r    = lane >> 3;             // row subgroup 0..7
    int c    = lane & 7;              // feature block (4 feats)
    if (node >= N_NODES) return;
    int cdeg = cnt[node];
    int cc   = cdeg < CAP ? cdeg : CAP;
    int slotv = (lane < cc) ? slots[node * CAP + lane] : 0;
    float a0 = 0.f, a1 = 0.f, a2 = 0.f, a3 = 0.f;
    float b0 = 0.f, b1 = 0.f, b2 = 0.f, b3 = 0.f;
    float c0 = 0.f, c1 = 0.f, c2 = 0.f, c3 = 0.f;
    float d0 = 0.f, d1 = 0.f, d2 = 0.f, d3 = 0.f;
    for (int i = 0; i < cc; i += 32) {
        int iA = i + r, iB = i + 8 + r, iC = i + 16 + r, iD = i + 24 + r;
        int sA = __shfl(slotv, iA & 63);
        int sB = __shfl(slotv, iB & 63);
        int sC = __shfl(slotv, iC & 63);
        int sD = __shfl(slotv, iD & 63);
        ushort4 vA = make_ushort4(0,0,0,0), vB = make_ushort4(0,0,0,0);
        ushort4 vC = make_ushort4(0,0,0,0), vD = make_ushort4(0,0,0,0);
        if (iA < cc) vA = *(const ushort4*)&y2b[sA * 32 + c * 4];
        if (iB < cc) vB = *(const ushort4*)&y2b[sB * 32 + c * 4];
        if (iC < cc) vC = *(const ushort4*)&y2b[sC * 32 + c * 4];
        if (iD < cc) vD = *(const ushort4*)&y2b[sD * 32 + c * 4];
        a0 += bf(vA.x); a1 += bf(vA.y); a2 += bf(vA.z); a3 += bf(vA.w);
        b0 += bf(vB.x); b1 += bf(vB.y); b2 += bf(vB.z); b3 += bf(vB.w);
        c0 += bf(vC.x); c1 += bf(vC.y); c2 += bf(vC.z); c3 += bf(vC.w);
        d0 += bf(vD.x); d1 += bf(vD.y); d2 += bf(vD.z); d3 += bf(vD.w);
    }
    a0 += b0 + c0 + d0; a1 += b1 + c1 + d1;
    a2 += b2 + c2 + d2; a3 += b3 + c3 + d3;
    a0 += __shfl_xor(a0, 8); a0 += __shfl_xor(a0, 16); a0 += __shfl_xor(a0, 32);
    a1 += __shfl_xor(a1, 8); a1 += __shfl_xor(a1, 16); a1 += __shfl_xor(a1, 32);
    a2 += __shfl_xor(a2, 8); a2 += __shfl_xor(a2, 16); a2 += __shfl_xor(a2, 32);
    a3 += __shfl_xor(a3, 8); a3 += __shfl_xor(a3, 16); a3 += __shfl_xor(a3, 32);
    if (r == 0) {
        float rd = 1.0f / fmaxf((float)cdeg, 1.0f);
        float4 zz = *(const float4*)&z[node * 32 + c * 4];
        *(float4*)&out[node * 32 + c * 4] = make_float4(
            a0 * rd + zz.x, a1 * rd + zz.y, a2 * rd + zz.z, a3 * rd + zz.w);
    }
}

// ------------- overflow apply (dual list, expected 0 iterations) ----------
__global__ __launch_bounds__(256) void ovf_apply_kernel(
    const float* __restrict__ feat, const int* __restrict__ cnt,
    const int* __restrict__ ovfA_cnt, const int* __restrict__ ovfA,
    const int* __restrict__ ovfB_cnt, const int* __restrict__ ovfB,
    float* __restrict__ m)
{
    int nA = *ovfA_cnt; if (nA > OVF_CAP) nA = OVF_CAP;
    int nB = *ovfB_cnt; if (nB > OVF_CAP) nB = OVF_CAP;
    int total = (nA + nB) * 64;
    for (int t = blockIdx.x * 256 + threadIdx.x; t < total; t += gridDim.x * 256) {
        int o = t >> 6, f = t & 63;
        const int* L = (o < nA) ? &ovfA[2 * o] : &ovfB[2 * (o - nA)];
        int src = L[0], dst = L[1];
        float rd = 1.0f / fmaxf((float)cnt[dst], 1.0f);
        atomicAdd(&m[dst * 64 + f], feat[src * 64 + f] * rd);
    }
}

__global__ __launch_bounds__(256) void ovf_apply32_kernel(
    const u16* __restrict__ y2b, const int* __restrict__ cnt,
    const int* __restrict__ ovfA_cnt, const int* __restrict__ ovfA,
    const int* __restrict__ ovfB_cnt, const int* __restrict__ ovfB,
    float* __restrict__ out)
{
    int nA = *ovfA_cnt; if (nA > OVF_CAP) nA = OVF_CAP;
    int nB = *ovfB_cnt; if (nB > OVF_CAP) nB = OVF_CAP;
    int total = (nA + nB) * 32;
    for (int t = blockIdx.x * 256 + threadIdx.x; t < total; t += gridDim.x * 256) {
        int o = t >> 5, f = t & 31;
        const int* L = (o < nA) ? &ovfA[2 * o] : &ovfB[2 * (o - nA)];
        int src = L[0], dst = L[1];
        float rd = 1.0f / fmaxf((float)cnt[dst], 1.0f);
        atomicAdd(&out[dst * 32 + f], bf(y2b[src * 32 + f]) * rd);
    }
}

// ------------- hi/lo truncate-split of 8 floats to bf16 frags -------------
__device__ inline void split8(float4 v0, float4 v1, s16x8& hi, s16x8& lo) {
    float vs[8] = {v0.x, v0.y, v0.z, v0.w, v1.x, v1.y, v1.z, v1.w};
    s16x8 h, l;
    #pragma unroll
    for (int j = 0; j < 8; j++) {
        unsigned b  = __float_as_uint(vs[j]);
        float    hf = __uint_as_float(b & 0xFFFF0000u);
        float    r  = vs[j] - hf;            // exact
        h[j] = (short)(b >> 16);
        l[j] = (short)(__float_as_uint(r) >> 16);
    }
    hi = h; lo = l;
}

// ------------- GEMM layer 1: h = relu([m|x] @ B1^T + b1), K=128 -----------
template <int MT>
__global__ __launch_bounds__(256) void gemm1_kernel(
    const float* __restrict__ Am, const float* __restrict__ Ax,
    const short* __restrict__ Bhi, const short* __restrict__ Blo,
    const float* __restrict__ bias, float* __restrict__ out)
{
    int wave = (blockIdx.x * 256 + threadIdx.x) >> 6;
    int lane = threadIdx.x & 63;
    int m0   = wave * (MT * 16);
    if (m0 >= N_NODES) return;
    int quad = lane >> 4, l16 = lane & 15;

    f32x4 acc[MT][4];
    #pragma unroll
    for (int mt = 0; mt < MT; mt++)
        #pragma unroll
        for (int nt = 0; nt < 4; nt++) acc[mt][nt] = (f32x4)0.0f;

    #pragma unroll
    for (int half = 0; half < 2; half++) {
        const float* src = half ? Ax : Am;
        #pragma unroll
        for (int sub = 0; sub < 2; sub++) {
            int kf = sub * 32 + quad * 8;
            int kc = half * 64 + sub * 32 + quad * 8;
            s16x8 ahi[MT], alo[MT];
            #pragma unroll
            for (int mt = 0; mt < MT; mt++) {
                int row = m0 + mt * 16 + l16;
                row = row < N_NODES ? row : N_NODES - 1;
                const float4* p = (const float4*)&src[row * 64 + kf];
                split8(p[0], p[1], ahi[mt], alo[mt]);
            }
            #pragma unroll
            for (int nt = 0; nt < 4; nt++) {
                int n = nt * 16 + l16;
                s16x8 bh = *(const s16x8*)&Bhi[n * 128 + kc];
                s16x8 bl = *(const s16x8*)&Blo[n * 128 + kc];
                #pragma unroll
                for (int mt = 0; mt < MT; mt++) {
                    acc[mt][nt] = __builtin_amdgcn_mfma_f32_16x16x32_bf16(ahi[mt], bh, acc[mt][nt], 0, 0, 0);
                    acc[mt][nt] = __builtin_amdgcn_mfma_f32_16x16x32_bf16(alo[mt], bh, acc[mt][nt], 0, 0, 0);
                    acc[mt][nt] = __builtin_amdgcn_mfma_f32_16x16x32_bf16(ahi[mt], bl, acc[mt][nt], 0, 0, 0);
                    acc[mt][nt] = __builtin_amdgcn_mfma_f32_16x16x32_bf16(alo[mt], bl, acc[mt][nt], 0, 0, 0);
                }
            }
        }
    }
    #pragma unroll
    for (int nt = 0; nt < 4; nt++) {
        float bv = bias[nt * 16 + l16];
        #pragma unroll
        for (int mt = 0; mt < MT; mt++)
            #pragma unroll
            for (int r = 0; r < 4; r++) {
                int row = m0 + mt * 16 + quad * 4 + r;
                if (row < N_NODES)
                    out[row * 64 + nt * 16 + l16] = fmaxf(acc[mt][nt][r] + bv, 0.0f);
            }
    }
}

// ------------- GEMM layer 2: y2b = bf16(h@W2l^T) ; z = h@W2r^T + b2 -------
template <int MT>
__global__ __launch_bounds__(256) void gemm2_kernel(
    const float* __restrict__ h,
    const short* __restrict__ Bhi, const short* __restrict__ Blo,  // [64,64]
    const float* __restrict__ b2,
    u16* __restrict__ y2b, float* __restrict__ z)                  // [N,32] each
{
    int wave = (blockIdx.x * 256 + threadIdx.x) >> 6;
    int lane = threadIdx.x & 63;
    int m0   = wave * (MT * 16);
    if (m0 >= N_NODES) return;
    int quad = lane >> 4, l16 = lane & 15;

    f32x4 acc[MT][4];
    #pragma unroll
    for (int mt = 0; mt < MT; mt++)
        #pragma unroll
        for (int nt = 0; nt < 4; nt++) acc[mt][nt] = (f32x4)0.0f;

    #pragma unroll
    for (int sub = 0; sub < 2; sub++) {
        int kf = sub * 32 + quad * 8;
        s16x8 ahi[MT], alo[MT];
        #pragma unroll
        for (int mt = 0; mt < MT; mt++) {
            int row = m0 + mt * 16 + l16;
            row = row < N_NODES ? row : N_NODES - 1;
            const float4* p = (const float4*)&h[row * 64 + kf];
            split8(p[0], p[1], ahi[mt], alo[mt]);
        }
        #pragma unroll
        for (int nt = 0; nt < 4; nt++) {
            int n = nt * 16 + l16;
            s16x8 bh = *(const s16x8*)&Bhi[n * 64 + kf];
            s16x8 bl = *(const s16x8*)&Blo[n * 64 + kf];
            #pragma unroll
            for (int mt = 0; mt < MT; mt++) {
                acc[mt][nt] = __builtin_amdgcn_mfma_f32_16x16x32_bf16(ahi[mt], bh, acc[mt][nt], 0, 0, 0);
                acc[mt][nt] = __builtin_amdgcn_mfma_f32_16x16x32_bf16(alo[mt], bh, acc[mt][nt], 0, 0, 0);
                acc[mt][nt] = __builtin_amdgcn_mfma_f32_16x16x32_bf16(ahi[mt], bl, acc[mt][nt], 0, 0, 0);
                acc[mt][nt] = __builtin_amdgcn_mfma_f32_16x16x32_bf16(alo[mt], bl, acc[mt][nt], 0, 0, 0);
            }
        }
    }
    #pragma unroll
    for (int nt = 0; nt < 4; nt++) {
        bool  isz = nt >= 2;
        int   col = (isz ? nt - 2 : nt) * 16 + l16;
        float bv  = isz ? b2[col] : 0.0f;
        #pragma unroll
        for (int mt = 0; mt < MT; mt++)
            #pragma unroll
            for (int r = 0; r < 4; r++) {
                int row = m0 + mt * 16 + quad * 4 + r;
                if (row < N_NODES) {
                    float v = acc[mt][nt][r] + bv;
                    if (isz) z[row * 32 + col] = v;
                    else     y2b[row * 32 + col] = f2bf(v);
                }
            }
    }
}

extern "C" void kernel_launch(void* const* d_in, const int* in_sizes, int n_in,
                              void* d_out, int out_size, void* d_ws, size_t ws_size,
                              hipStream_t stream) {
    const float* x   = (const float*)d_in[0];
    const int*   ei1 = (const int*)d_in[1];
    const int*   ei2 = (const int*)d_in[3];
    const float* W1l = (const float*)d_in[5];
    const float* b1  = (const float*)d_in[6];
    const float* W1r = (const float*)d_in[7];
    const float* W2l = (const float*)d_in[8];
    const float* b2  = (const float*)d_in[9];
    const float* W2r = (const float*)d_in[10];
    float* out = (float*)d_out;

    // workspace layout. Aliases: barr -> m region (dead before gather writes
    // m); z/y2b -> m region (dead after gemm1); xb -> h region (dead before
    // gemm1 writes h).
    const size_t off_cnt   = 0;                                    // int[N]
    const size_t off_misc  = 400128;
    const size_t off_ovfAc = off_misc + 0;
    const size_t off_ovfBc = off_misc + 4;
    const size_t off_bcur  = off_misc + 256;                       // int[NB]
    const size_t off_ovfA  = off_misc + 1280;                      // 32 KB
    const size_t off_ovfB  = off_misc + 1280 + 8 * OVF_CAP;        // 32 KB
    const size_t off_slots = 467200;                               // int[N*CAP]
    const size_t off_m     = off_slots + (size_t)N_NODES * CAP * 4;
    const size_t off_h     = off_m + (size_t)N_NODES * 64 * 4;
    const size_t off_B1hi  = off_h + (size_t)N_NODES * 64 * 4;
    const size_t off_B1lo  = off_B1hi + 64 * 128 * 2;
    const size_t off_B2hi  = off_B1lo + 64 * 128 * 2;
    const size_t off_B2lo  = off_B2hi + 64 * 64 * 2;

    char*  ws     = (char*)d_ws;
    int*   cnt    = (int*)(ws + off_cnt);
    int*   ovfA_c = (int*)(ws + off_ovfAc);
    int*   ovfB_c = (int*)(ws + off_ovfBc);
    int*   bcur   = (int*)(ws + off_bcur);
    int*   ovfA   = (int*)(ws + off_ovfA);
    int*   ovfB   = (int*)(ws + off_ovfB);
    int*   slots  = (int*)(ws + off_slots);
    uint2* barr   = (uint2*)(ws + off_m);                          // alias m
    float* m      = (float*)(ws + off_m);
    float* h      = (float*)(ws + off_h);
    u16*   xb     = (u16*)(ws + off_h);                            // alias h
    float* z      = (float*)(ws + off_m);                          // alias m
    u16*   y2b    = (u16*)(ws + off_m + (size_t)N_NODES * 32 * 4); // alias m
    short* B1hi   = (short*)(ws + off_B1hi);
    short* B1lo   = (short*)(ws + off_B1lo);
    short* B2hi   = (short*)(ws + off_B2hi);
    short* B2lo   = (short*)(ws + off_B2lo);

    // zero counters + bucket cursors (+ovf lists) only (~67 KB)
    hipMemsetAsync(ws + off_misc, 0, off_slots - off_misc, stream);

    // prep: x->bf16 (6250 blocks) + weight hi/lo split (48 blocks)
    prep_kernel<<<6250 + 48, 256, 0, stream>>>(
        x, xb, W1l, W1r, W2l, W2r, B1hi, B1lo, B2hi, B2lo);

    // bucket build (shared by both layers)
    binA_kernel<<<(E_TOT + EPB_A - 1) / EPB_A, 256, 0, stream>>>(
        ei1, ei2, barr, bcur, ovfA_c, ovfA);
    binB_kernel<<<NB, 1024, 0, stream>>>(barr, bcur, cnt, slots, ovfB_c, ovfB);
    ovf_fix_kernel<<<OVF_CAP / 256, 256, 0, stream>>>(ovfA_c, ovfA, cnt);

    // layer 1: gather-mean(bf16 x) -> m ; h = relu([m|x]@B1^T + b1)
    gather_mean_kernel<<<N_NODES / 4, 256, 0, stream>>>(xb, cnt, slots, m);
    ovf_apply_kernel<<<16, 256, 0, stream>>>(
        x, cnt, ovfA_c, ovfA, ovfB_c, ovfB, m);
    {
        int waves = (N_NODES + 31) / 32;   // MT=2
        gemm1_kernel<2><<<(waves + 3) / 4, 256, 0, stream>>>(
            m, x, B1hi, B1lo, b1, h);
    }

    // layer 2 (transform-first): y2b = bf16(h@W2l^T), z = h@W2r^T + b2;
    // out = gather-mean(y2b) + z
    {
        int waves = (N_NODES + 63) / 64;   // MT=4
        gemm2_kernel<4><<<(waves + 3) / 4, 256, 0, stream>>>(
            h, B2hi, B2lo, b2, y2b, z);
    }
    gather_mean32_kernel<<<N_NODES / 4, 256, 0, stream>>>(y2b, z, cnt, slots, out);
    ovf_apply32_kernel<<<16, 256, 0, stream>>>(
        y2b, cnt, ovfA_c, ovfA, ovfB_c, ovfB, out);
}

// Round 13
// 246.047 us; speedup vs baseline: 1.5727x; 1.0362x over previous
//
#include <hip/hip_runtime.h>

// GraphSAGE 2-layer, mean aggregation, fp32.
// R12 evidence: top-5 is all harness ws re-poison (43 us/iter, fixed);
// ours ~210 us. R13: (1) h stored bf16 (h feeds ONLY gemm2 -> A-operand
// exact in bf16: gemm2 2-term MFMA, no A-split, half reads; gemm1 half
// writes); (2) binA keeps its 8 edges/thread in registers across phases
// (one global edge read instead of two). Else identical to R12
// (proven: 255 us, absmax 7.8e-3).

constexpr int N_NODES = 100000;
constexpr int E_HALF  = 800000;
constexpr int E_TOT   = 2 * E_HALF;
constexpr int CAP     = 64;      // slots per node
constexpr int OVF_CAP = 4096;    // overflow capacity (expected use: 0)
constexpr int NB      = 200;     // coarse buckets
constexpr int NPB     = 500;     // nodes per bucket
constexpr int BCAP    = 12288;   // edges per bucket (mean 8000, +48 sigma)
constexpr int EPB_A   = 2048;    // edges per pass-A block -> 782 blocks
constexpr int EPT_A   = EPB_A / 256;   // 8 edges per thread

typedef short  s16x8 __attribute__((ext_vector_type(8)));
typedef float  f32x4 __attribute__((ext_vector_type(4)));
typedef unsigned short u16;

__device__ inline float bf(u16 u) { return __uint_as_float(((unsigned)u) << 16); }
__device__ inline u16 f2bf(float v) {          // round-to-nearest-even bf16
    unsigned b = __float_as_uint(v);
    b += 0x7FFFu + ((b >> 16) & 1u);
    return (u16)(b >> 16);
}

// ------------- pass A: bin edges, registers across phases, LDS-staged -----
__global__ __launch_bounds__(256) void binA_kernel(
    const int* __restrict__ ei1, const int* __restrict__ ei2,
    uint2* __restrict__ barr, int* __restrict__ bcur,
    int* __restrict__ ovfA_cnt, int* __restrict__ ovfA)
{
    __shared__ int   hist[NB], base[NB], cur[NB], lofs[NB];
    __shared__ int   scan[256];
    __shared__ int   aux[EPB_A];
    __shared__ uint2 staged[EPB_A];
    int tid = threadIdx.x;
    for (int t = tid; t < NB; t += 256) { hist[t] = 0; cur[t] = 0; }
    __syncthreads();

    // phase 1: load edges once into registers + histogram
    int e0 = blockIdx.x * EPB_A;
    uint2 myE[EPT_A];
    int   myB[EPT_A];
    #pragma unroll
    for (int k = 0; k < EPT_A; k++) {
        int e = e0 + k * 256 + tid;
        myB[k] = -1;
        if (e < E_TOT) {
            const int* ei = (e < E_HALF) ? ei1 : ei2;
            int ee = (e < E_HALF) ? e : e - E_HALF;
            int dst = ei[E_HALF + ee];
            int src = ei[ee];
            myE[k] = make_uint2((unsigned)src, (unsigned)dst);
            myB[k] = dst / NPB;
            atomicAdd(&hist[myB[k]], 1);
        }
    }
    __syncthreads();

    // phase 2a: block-exclusive scan of hist (Hillis-Steele over 256)
    int v = (tid < NB) ? hist[tid] : 0;
    scan[tid] = v;
    __syncthreads();
    #pragma unroll
    for (int off = 1; off < 256; off <<= 1) {
        int u = (tid >= off) ? scan[tid - off] : 0;
        __syncthreads();
        scan[tid] += u;
        __syncthreads();
    }
    if (tid < NB) lofs[tid] = scan[tid] - v;
    // phase 2b: reserve global windows (200 fabric atomics/block)
    if (tid < NB) base[tid] = atomicAdd(&bcur[tid], hist[tid]);
    __syncthreads();

    // phase 3: stage edges into LDS, bucket-sorted; record global addr
    #pragma unroll
    for (int k = 0; k < EPT_A; k++) {
        int b = myB[k];
        if (b < 0) continue;
        int rank = atomicAdd(&cur[b], 1);          // LDS atomic
        int p    = lofs[b] + rank;
        int gpos = base[b] + rank;
        if (gpos < BCAP) {
            staged[p] = myE[k];
            aux[p]    = b * BCAP + gpos;
        } else {
            aux[p] = -1;
            int o = atomicAdd(ovfA_cnt, 1);
            if (o < OVF_CAP) {
                ovfA[2 * o] = (int)myE[k].x; ovfA[2 * o + 1] = (int)myE[k].y;
            }
        }
    }
    __syncthreads();

    // phase 4: dense write-out (runs are contiguous -> coalesced)
    int tot = scan[255];
    for (int i = tid; i < tot; i += 256) {
        int a = aux[i];
        if (a >= 0) barr[a] = staged[i];
    }
}

// ------------- pass B: per-bucket slot build with LDS counters ------------
__global__ __launch_bounds__(1024) void binB_kernel(
    const uint2* __restrict__ barr, const int* __restrict__ bcur,
    int* __restrict__ cnt, int* __restrict__ slots,
    int* __restrict__ ovfB_cnt, int* __restrict__ ovfB)
{
    __shared__ int lcnt[NPB];
    int tid = threadIdx.x, b = blockIdx.x;
    for (int t = tid; t < NPB; t += 1024) lcnt[t] = 0;
    __syncthreads();
    int nE = bcur[b]; if (nE > BCAP) nE = BCAP;
    int dbase = b * NPB;
    for (int i = tid; i < nE; i += 1024) {
        uint2 e = barr[b * BCAP + i];
        int dst = (int)e.y;
        int pos = atomicAdd(&lcnt[dst - dbase], 1);   // LDS atomic
        if (pos < CAP) {
            slots[dst * CAP + pos] = (int)e.x;        // L2-resident window
        } else {
            int o = atomicAdd(ovfB_cnt, 1);
            if (o < OVF_CAP) { ovfB[2 * o] = (int)e.x; ovfB[2 * o + 1] = dst; }
        }
    }
    __syncthreads();
    for (int t = tid; t < NPB; t += 1024) {
        int n = dbase + t;
        if (n < N_NODES) cnt[n] = lcnt[t];
    }
}

// ------------- cnt fix for pass-A overflow edges (expected 0) -------------
__global__ __launch_bounds__(256) void ovf_fix_kernel(
    const int* __restrict__ ovfA_cnt, const int* __restrict__ ovfA,
    int* __restrict__ cnt)
{
    int n = *ovfA_cnt; if (n > OVF_CAP) n = OVF_CAP;
    int t = blockIdx.x * 256 + threadIdx.x;
    if (t < n) atomicAdd(&cnt[ovfA[2 * t + 1]], 1);
}

// ------------- prep: x -> bf16 (blocks 0..6249) + weight split (48) -------
__global__ __launch_bounds__(256) void prep_kernel(
    const float* __restrict__ x, u16* __restrict__ xb,
    const float* __restrict__ W1l, const float* __restrict__ W1r,
    const float* __restrict__ W2l, const float* __restrict__ W2r,
    short* __restrict__ B1hi, short* __restrict__ B1lo,
    short* __restrict__ B2hi, short* __restrict__ B2lo)
{
    int blk = blockIdx.x;
    if (blk < 6250) {                        // N*16 float4 = 6250*256 exact
        int i = blk * 256 + threadIdx.x;
        float4 v = ((const float4*)x)[i];
        ushort4 rr;
        rr.x = f2bf(v.x); rr.y = f2bf(v.y); rr.z = f2bf(v.z); rr.w = f2bf(v.w);
        ((ushort4*)xb)[i] = rr;
        return;
    }
    int i = (blk - 6250) * 256 + threadIdx.x;   // 48*256 = 12288 exact
    float v; short* ph; short* pl; int idx;
    if (i < 64 * 128) {
        int o = i >> 7, k = i & 127;
        v = (k < 64) ? W1l[o * 64 + k] : W1r[o * 64 + (k - 64)];
        ph = B1hi; pl = B1lo; idx = i;
    } else {
        int j = i - 64 * 128;                   // j < 64*64
        int o = j >> 6, k = j & 63;
        v = (o < 32) ? W2l[o * 64 + k] : W2r[(o - 32) * 64 + k];
        ph = B2hi; pl = B2lo; idx = j;
    }
    unsigned b  = __float_as_uint(v);
    float    hf = __uint_as_float(b & 0xFFFF0000u);
    float    r  = v - hf;
    ph[idx] = (short)(b >> 16);
    pl[idx] = (short)(__float_as_uint(r) >> 16);
}

// ------------- gather-mean 64-wide: wave/node, 4 loads/lane in flight -----
__global__ __launch_bounds__(256) void gather_mean_kernel(
    const u16*  __restrict__ xb,      // [N,64] bf16
    const int*  __restrict__ cnt,     // [N]
    const int*  __restrict__ slots,   // [N,CAP]
    float*      __restrict__ m)       // [N,64] mean (fp32)
{
    int node = blockIdx.x * 4 + (threadIdx.x >> 6);
    int lane = threadIdx.x & 63;
    int r    = lane >> 4;             // row subgroup 0..3
    int c    = lane & 15;             // feature block (4 feats)
    if (node >= N_NODES) return;
    int cdeg = cnt[node];
    int cc   = cdeg < CAP ? cdeg : CAP;
    int slotv = (lane < cc) ? slots[node * CAP + lane] : 0;
    float a0 = 0.f, a1 = 0.f, a2 = 0.f, a3 = 0.f;
    float b0 = 0.f, b1 = 0.f, b2 = 0.f, b3 = 0.f;
    float c0 = 0.f, c1 = 0.f, c2 = 0.f, c3 = 0.f;
    float d0 = 0.f, d1 = 0.f, d2 = 0.f, d3 = 0.f;
    for (int i = 0; i < cc; i += 16) {
        int iA = i + r, iB = i + 4 + r, iC = i + 8 + r, iD = i + 12 + r;
        int sA = __shfl(slotv, iA & 63);
        int sB = __shfl(slotv, iB & 63);
        int sC = __shfl(slotv, iC & 63);
        int sD = __shfl(slotv, iD & 63);
        ushort4 vA = make_ushort4(0,0,0,0), vB = make_ushort4(0,0,0,0);
        ushort4 vC = make_ushort4(0,0,0,0), vD = make_ushort4(0,0,0,0);
        if (iA < cc) vA = *(const ushort4*)&xb[sA * 64 + c * 4];
        if (iB < cc) vB = *(const ushort4*)&xb[sB * 64 + c * 4];
        if (iC < cc) vC = *(const ushort4*)&xb[sC * 64 + c * 4];
        if (iD < cc) vD = *(const ushort4*)&xb[sD * 64 + c * 4];
        a0 += bf(vA.x); a1 += bf(vA.y); a2 += bf(vA.z); a3 += bf(vA.w);
        b0 += bf(vB.x); b1 += bf(vB.y); b2 += bf(vB.z); b3 += bf(vB.w);
        c0 += bf(vC.x); c1 += bf(vC.y); c2 += bf(vC.z); c3 += bf(vC.w);
        d0 += bf(vD.x); d1 += bf(vD.y); d2 += bf(vD.z); d3 += bf(vD.w);
    }
    a0 += b0 + c0 + d0; a1 += b1 + c1 + d1;
    a2 += b2 + c2 + d2; a3 += b3 + c3 + d3;
    a0 += __shfl_xor(a0, 16); a0 += __shfl_xor(a0, 32);
    a1 += __shfl_xor(a1, 16); a1 += __shfl_xor(a1, 32);
    a2 += __shfl_xor(a2, 16); a2 += __shfl_xor(a2, 32);
    a3 += __shfl_xor(a3, 16); a3 += __shfl_xor(a3, 32);
    if (r == 0) {
        float rd = 1.0f / fmaxf((float)cdeg, 1.0f);
        *(float4*)&m[node * 64 + c * 4] =
            make_float4(a0 * rd, a1 * rd, a2 * rd, a3 * rd);
    }
}

// ------------- gather-mean 32-wide + add z -> out, 4 loads/lane -----------
__global__ __launch_bounds__(256) void gather_mean32_kernel(
    const u16*  __restrict__ y2b,     // [N,32] bf16
    const float* __restrict__ z,      // [N,32] self term (bias included)
    const int*  __restrict__ cnt,
    const int*  __restrict__ slots,
    float*      __restrict__ out)     // [N,32]
{
    int node = blockIdx.x * 4 + (threadIdx.x >> 6);
    int lane = threadIdx.x & 63;
    int r    = lane >> 3;             // row subgroup 0..7
    int c    = lane & 7;              // feature block (4 feats)
    if (node >= N_NODES) return;
    int cdeg = cnt[node];
    int cc   = cdeg < CAP ? cdeg : CAP;
    int slotv = (lane < cc) ? slots[node * CAP + lane] : 0;
    float a0 = 0.f, a1 = 0.f, a2 = 0.f, a3 = 0.f;
    float b0 = 0.f, b1 = 0.f, b2 = 0.f, b3 = 0.f;
    float c0 = 0.f, c1 = 0.f, c2 = 0.f, c3 = 0.f;
    float d0 = 0.f, d1 = 0.f, d2 = 0.f, d3 = 0.f;
    for (int i = 0; i < cc; i += 32) {
        int iA = i + r, iB = i + 8 + r, iC = i + 16 + r, iD = i + 24 + r;
        int sA = __shfl(slotv, iA & 63);
        int sB = __shfl(slotv, iB & 63);
        int sC = __shfl(slotv, iC & 63);
        int sD = __shfl(slotv, iD & 63);
        ushort4 vA = make_ushort4(0,0,0,0), vB = make_ushort4(0,0,0,0);
        ushort4 vC = make_ushort4(0,0,0,0), vD = make_ushort4(0,0,0,0);
        if (iA < cc) vA = *(const ushort4*)&y2b[sA * 32 + c * 4];
        if (iB < cc) vB = *(const ushort4*)&y2b[sB * 32 + c * 4];
        if (iC < cc) vC = *(const ushort4*)&y2b[sC * 32 + c * 4];
        if (iD < cc) vD = *(const ushort4*)&y2b[sD * 32 + c * 4];
        a0 += bf(vA.x); a1 += bf(vA.y); a2 += bf(vA.z); a3 += bf(vA.w);
        b0 += bf(vB.x); b1 += bf(vB.y); b2 += bf(vB.z); b3 += bf(vB.w);
        c0 += bf(vC.x); c1 += bf(vC.y); c2 += bf(vC.z); c3 += bf(vC.w);
        d0 += bf(vD.x); d1 += bf(vD.y); d2 += bf(vD.z); d3 += bf(vD.w);
    }
    a0 += b0 + c0 + d0; a1 += b1 + c1 + d1;
    a2 += b2 + c2 + d2; a3 += b3 + c3 + d3;
    a0 += __shfl_xor(a0, 8); a0 += __shfl_xor(a0, 16); a0 += __shfl_xor(a0, 32);
    a1 += __shfl_xor(a1, 8); a1 += __shfl_xor(a1, 16); a1 += __shfl_xor(a1, 32);
    a2 += __shfl_xor(a2, 8); a2 += __shfl_xor(a2, 16); a2 += __shfl_xor(a2, 32);
    a3 += __shfl_xor(a3, 8); a3 += __shfl_xor(a3, 16); a3 += __shfl_xor(a3, 32);
    if (r == 0) {
        float rd = 1.0f / fmaxf((float)cdeg, 1.0f);
        float4 zz = *(const float4*)&z[node * 32 + c * 4];
        *(float4*)&out[node * 32 + c * 4] = make_float4(
            a0 * rd + zz.x, a1 * rd + zz.y, a2 * rd + zz.z, a3 * rd + zz.w);
    }
}

// ------------- overflow apply (dual list, expected 0 iterations) ----------
__global__ __launch_bounds__(256) void ovf_apply_kernel(
    const float* __restrict__ feat, const int* __restrict__ cnt,
    const int* __restrict__ ovfA_cnt, const int* __restrict__ ovfA,
    const int* __restrict__ ovfB_cnt, const int* __restrict__ ovfB,
    float* __restrict__ m)
{
    int nA = *ovfA_cnt; if (nA > OVF_CAP) nA = OVF_CAP;
    int nB = *ovfB_cnt; if (nB > OVF_CAP) nB = OVF_CAP;
    int total = (nA + nB) * 64;
    for (int t = blockIdx.x * 256 + threadIdx.x; t < total; t += gridDim.x * 256) {
        int o = t >> 6, f = t & 63;
        const int* L = (o < nA) ? &ovfA[2 * o] : &ovfB[2 * (o - nA)];
        int src = L[0], dst = L[1];
        float rd = 1.0f / fmaxf((float)cnt[dst], 1.0f);
        atomicAdd(&m[dst * 64 + f], feat[src * 64 + f] * rd);
    }
}

__global__ __launch_bounds__(256) void ovf_apply32_kernel(
    const u16* __restrict__ y2b, const int* __restrict__ cnt,
    const int* __restrict__ ovfA_cnt, const int* __restrict__ ovfA,
    const int* __restrict__ ovfB_cnt, const int* __restrict__ ovfB,
    float* __restrict__ out)
{
    int nA = *ovfA_cnt; if (nA > OVF_CAP) nA = OVF_CAP;
    int nB = *ovfB_cnt; if (nB > OVF_CAP) nB = OVF_CAP;
    int total = (nA + nB) * 32;
    for (int t = blockIdx.x * 256 + threadIdx.x; t < total; t += gridDim.x * 256) {
        int o = t >> 5, f = t & 31;
        const int* L = (o < nA) ? &ovfA[2 * o] : &ovfB[2 * (o - nA)];
        int src = L[0], dst = L[1];
        float rd = 1.0f / fmaxf((float)cnt[dst], 1.0f);
        atomicAdd(&out[dst * 32 + f], bf(y2b[src * 32 + f]) * rd);
    }
}

// ------------- hi/lo truncate-split of 8 floats to bf16 frags -------------
__device__ inline void split8(float4 v0, float4 v1, s16x8& hi, s16x8& lo) {
    float vs[8] = {v0.x, v0.y, v0.z, v0.w, v1.x, v1.y, v1.z, v1.w};
    s16x8 h, l;
    #pragma unroll
    for (int j = 0; j < 8; j++) {
        unsigned b  = __float_as_uint(vs[j]);
        float    hf = __uint_as_float(b & 0xFFFF0000u);
        float    r  = vs[j] - hf;            // exact
        h[j] = (short)(b >> 16);
        l[j] = (short)(__float_as_uint(r) >> 16);
    }
    hi = h; lo = l;
}

// ------------- GEMM layer 1: hb = bf16(relu([m|x] @ B1^T + b1)), K=128 ----
template <int MT>
__global__ __launch_bounds__(256) void gemm1_kernel(
    const float* __restrict__ Am, const float* __restrict__ Ax,
    const short* __restrict__ Bhi, const short* __restrict__ Blo,
    const float* __restrict__ bias, u16* __restrict__ hb)
{
    int wave = (blockIdx.x * 256 + threadIdx.x) >> 6;
    int lane = threadIdx.x & 63;
    int m0   = wave * (MT * 16);
    if (m0 >= N_NODES) return;
    int quad = lane >> 4, l16 = lane & 15;

    f32x4 acc[MT][4];
    #pragma unroll
    for (int mt = 0; mt < MT; mt++)
        #pragma unroll
        for (int nt = 0; nt < 4; nt++) acc[mt][nt] = (f32x4)0.0f;

    #pragma unroll
    for (int half = 0; half < 2; half++) {
        const float* src = half ? Ax : Am;
        #pragma unroll
        for (int sub = 0; sub < 2; sub++) {
            int kf = sub * 32 + quad * 8;
            int kc = half * 64 + sub * 32 + quad * 8;
            s16x8 ahi[MT], alo[MT];
            #pragma unroll
            for (int mt = 0; mt < MT; mt++) {
                int row = m0 + mt * 16 + l16;
                row = row < N_NODES ? row : N_NODES - 1;
                const float4* p = (const float4*)&src[row * 64 + kf];
                split8(p[0], p[1], ahi[mt], alo[mt]);
            }
            #pragma unroll
            for (int nt = 0; nt < 4; nt++) {
                int n = nt * 16 + l16;
                s16x8 bh = *(const s16x8*)&Bhi[n * 128 + kc];
                s16x8 bl = *(const s16x8*)&Blo[n * 128 + kc];
                #pragma unroll
                for (int mt = 0; mt < MT; mt++) {
                    acc[mt][nt] = __builtin_amdgcn_mfma_f32_16x16x32_bf16(ahi[mt], bh, acc[mt][nt], 0, 0, 0);
                    acc[mt][nt] = __builtin_amdgcn_mfma_f32_16x16x32_bf16(alo[mt], bh, acc[mt][nt], 0, 0, 0);
                    acc[mt][nt] = __builtin_amdgcn_mfma_f32_16x16x32_bf16(ahi[mt], bl, acc[mt][nt], 0, 0, 0);
                    acc[mt][nt] = __builtin_amdgcn_mfma_f32_16x16x32_bf16(alo[mt], bl, acc[mt][nt], 0, 0, 0);
                }
            }
        }
    }
    #pragma unroll
    for (int nt = 0; nt < 4; nt++) {
        float bv = bias[nt * 16 + l16];
        #pragma unroll
        for (int mt = 0; mt < MT; mt++)
            #pragma unroll
            for (int r = 0; r < 4; r++) {
                int row = m0 + mt * 16 + quad * 4 + r;
                if (row < N_NODES)
                    hb[row * 64 + nt * 16 + l16] =
                        f2bf(fmaxf(acc[mt][nt][r] + bv, 0.0f));
            }
    }
}

// ------------- GEMM layer 2: y2b/z from bf16 hb, 2-term MFMA, K=64 --------
template <int MT>
__global__ __launch_bounds__(256) void gemm2_kernel(
    const u16* __restrict__ hb,                                    // [N,64] bf16
    const short* __restrict__ Bhi, const short* __restrict__ Blo,  // [64,64]
    const float* __restrict__ b2,
    u16* __restrict__ y2b, float* __restrict__ z)                  // [N,32] each
{
    int wave = (blockIdx.x * 256 + threadIdx.x) >> 6;
    int lane = threadIdx.x & 63;
    int m0   = wave * (MT * 16);
    if (m0 >= N_NODES) return;
    int quad = lane >> 4, l16 = lane & 15;

    f32x4 acc[MT][4];
    #pragma unroll
    for (int mt = 0; mt < MT; mt++)
        #pragma unroll
        for (int nt = 0; nt < 4; nt++) acc[mt][nt] = (f32x4)0.0f;

    #pragma unroll
    for (int sub = 0; sub < 2; sub++) {
        int kf = sub * 32 + quad * 8;
        s16x8 a[MT];
        #pragma unroll
        for (int mt = 0; mt < MT; mt++) {
            int row = m0 + mt * 16 + l16;
            row = row < N_NODES ? row : N_NODES - 1;
            a[mt] = *(const s16x8*)&hb[row * 64 + kf];   // exact bf16 A
        }
        #pragma unroll
        for (int nt = 0; nt < 4; nt++) {
            int n = nt * 16 + l16;
            s16x8 bh = *(const s16x8*)&Bhi[n * 64 + kf];
            s16x8 bl = *(const s16x8*)&Blo[n * 64 + kf];
            #pragma unroll
            for (int mt = 0; mt < MT; mt++) {
                acc[mt][nt] = __builtin_amdgcn_mfma_f32_16x16x32_bf16(a[mt], bh, acc[mt][nt], 0, 0, 0);
                acc[mt][nt] = __builtin_amdgcn_mfma_f32_16x16x32_bf16(a[mt], bl, acc[mt][nt], 0, 0, 0);
            }
        }
    }
    #pragma unroll
    for (int nt = 0; nt < 4; nt++) {
        bool  isz = nt >= 2;
        int   col = (isz ? nt - 2 : nt) * 16 + l16;
        float bv  = isz ? b2[col] : 0.0f;
        #pragma unroll
        for (int mt = 0; mt < MT; mt++)
            #pragma unroll
            for (int r = 0; r < 4; r++) {
                int row = m0 + mt * 16 + quad * 4 + r;
                if (row < N_NODES) {
                    float v = acc[mt][nt][r] + bv;
                    if (isz) z[row * 32 + col] = v;
                    else     y2b[row * 32 + col] = f2bf(v);
                }
            }
    }
}

extern "C" void kernel_launch(void* const* d_in, const int* in_sizes, int n_in,
                              void* d_out, int out_size, void* d_ws, size_t ws_size,
                              hipStream_t stream) {
    const float* x   = (const float*)d_in[0];
    const int*   ei1 = (const int*)d_in[1];
    const int*   ei2 = (const int*)d_in[3];
    const float* W1l = (const float*)d_in[5];
    const float* b1  = (const float*)d_in[6];
    const float* W1r = (const float*)d_in[7];
    const float* W2l = (const float*)d_in[8];
    const float* b2  = (const float*)d_in[9];
    const float* W2r = (const float*)d_in[10];
    float* out = (float*)d_out;

    // workspace layout. Aliases: barr -> m region (dead before gather writes
    // m); z/y2b -> m region (dead after gemm1). Old h region (25.6 MB) now
    // holds xb (bf16, first 12.8 MB) and hb (bf16, second 12.8 MB) — no
    // overlap.
    const size_t off_cnt   = 0;                                    // int[N]
    const size_t off_misc  = 400128;
    const size_t off_ovfAc = off_misc + 0;
    const size_t off_ovfBc = off_misc + 4;
    const size_t off_bcur  = off_misc + 256;                       // int[NB]
    const size_t off_ovfA  = off_misc + 1280;                      // 32 KB
    const size_t off_ovfB  = off_misc + 1280 + 8 * OVF_CAP;        // 32 KB
    const size_t off_slots = 467200;                               // int[N*CAP]
    const size_t off_m     = off_slots + (size_t)N_NODES * CAP * 4;
    const size_t off_h     = off_m + (size_t)N_NODES * 64 * 4;
    const size_t off_hb    = off_h + (size_t)N_NODES * 64 * 2;     // 2nd half
    const size_t off_B1hi  = off_h + (size_t)N_NODES * 64 * 4;
    const size_t off_B1lo  = off_B1hi + 64 * 128 * 2;
    const size_t off_B2hi  = off_B1lo + 64 * 128 * 2;
    const size_t off_B2lo  = off_B2hi + 64 * 64 * 2;

    char*  ws     = (char*)d_ws;
    int*   cnt    = (int*)(ws + off_cnt);
    int*   ovfA_c = (int*)(ws + off_ovfAc);
    int*   ovfB_c = (int*)(ws + off_ovfBc);
    int*   bcur   = (int*)(ws + off_bcur);
    int*   ovfA   = (int*)(ws + off_ovfA);
    int*   ovfB   = (int*)(ws + off_ovfB);
    int*   slots  = (int*)(ws + off_slots);
    uint2* barr   = (uint2*)(ws + off_m);                          // alias m
    float* m      = (float*)(ws + off_m);
    u16*   xb     = (u16*)(ws + off_h);                            // 12.8 MB
    u16*   hb     = (u16*)(ws + off_hb);                           // 12.8 MB
    float* z      = (float*)(ws + off_m);                          // alias m
    u16*   y2b    = (u16*)(ws + off_m + (size_t)N_NODES * 32 * 4); // alias m
    short* B1hi   = (short*)(ws + off_B1hi);
    short* B1lo   = (short*)(ws + off_B1lo);
    short* B2hi   = (short*)(ws + off_B2hi);
    short* B2lo   = (short*)(ws + off_B2lo);

    // zero counters + bucket cursors (+ovf lists) only (~67 KB)
    hipMemsetAsync(ws + off_misc, 0, off_slots - off_misc, stream);

    // prep: x->bf16 (6250 blocks) + weight hi/lo split (48 blocks)
    prep_kernel<<<6250 + 48, 256, 0, stream>>>(
        x, xb, W1l, W1r, W2l, W2r, B1hi, B1lo, B2hi, B2lo);

    // bucket build (shared by both layers)
    binA_kernel<<<(E_TOT + EPB_A - 1) / EPB_A, 256, 0, stream>>>(
        ei1, ei2, barr, bcur, ovfA_c, ovfA);
    binB_kernel<<<NB, 1024, 0, stream>>>(barr, bcur, cnt, slots, ovfB_c, ovfB);
    ovf_fix_kernel<<<OVF_CAP / 256, 256, 0, stream>>>(ovfA_c, ovfA, cnt);

    // layer 1: gather-mean(bf16 x) -> m ; hb = bf16(relu([m|x]@B1^T + b1))
    gather_mean_kernel<<<N_NODES / 4, 256, 0, stream>>>(xb, cnt, slots, m);
    ovf_apply_kernel<<<16, 256, 0, stream>>>(
        x, cnt, ovfA_c, ovfA, ovfB_c, ovfB, m);
    {
        int waves = (N_NODES + 31) / 32;   // MT=2
        gemm1_kernel<2><<<(waves + 3) / 4, 256, 0, stream>>>(
            m, x, B1hi, B1lo, b1, hb);
    }

    // layer 2 (transform-first): y2b = bf16(hb@W2l^T), z = hb@W2r^T + b2;
    // out = gather-mean(y2b) + z
    {
        int waves = (N_NODES + 63) / 64;   // MT=4
        gemm2_kernel<4><<<(waves + 3) / 4, 256, 0, stream>>>(
            hb, B2hi, B2lo, b2, y2b, z);
    }
    gather_mean32_kernel<<<N_NODES / 4, 256, 0, stream>>>(y2b, z, cnt, slots, out);
    ovf_apply32_kernel<<<16, 256, 0, stream>>>(
        y2b, cnt, ovfA_c, ovfA, ovfB_c, ovfB, out);
}